// Round 1
// baseline (1158.762 us; speedup 1.0000x reference)
//
#include <hip/hip_runtime.h>
#include <stdint.h>

#define HH 112
#define WW 112
#define CC 512
#define BB 4
#define LLEN (HH*WW)
#define NTOK (BB*LLEN)   // 50176
#define NHEADS 8
#define HD 64
#define HIDDEN 2048

typedef __bf16 bf16x8 __attribute__((ext_vector_type(8)));
typedef float f32x4 __attribute__((ext_vector_type(4)));

__device__ __forceinline__ unsigned short f2bf(float x) {
  uint32_t u = __float_as_uint(x);
  u += 0x7fffu + ((u >> 16) & 1u);
  return (unsigned short)(u >> 16);
}
__device__ __forceinline__ float bf2f(unsigned short h) {
  return __uint_as_float((uint32_t)h << 16);
}

// ---------------- weight transpose (K,N) f32 -> (N,K) bf16 ----------------
__global__ __launch_bounds__(256) void wtranspose_kernel(
    const float* __restrict__ w, unsigned short* __restrict__ wt, int K, int N) {
  int idx = blockIdx.x * 256 + threadIdx.x;
  if (idx >= K * N) return;
  int k = idx / N, n = idx - k * N;
  wt[(size_t)n * K + k] = f2bf(w[idx]);
}

// ---------------- depthwise 3x3 conv + bias + residual ----------------
__global__ __launch_bounds__(256) void cpe_kernel(
    const float* __restrict__ x, const float* __restrict__ w,
    const float* __restrict__ bias, float* __restrict__ out) {
  int tid = blockIdx.x * 256 + threadIdx.x;
  int c = (tid & 127) << 2;      // channel chunk of 4
  int pix = tid >> 7;
  int xx = pix % WW; int t2 = pix / WW; int yy = t2 % HH; int bb = t2 / HH;
  float4 bv = *(const float4*)(&bias[c]);
  float ax = bv.x, ay = bv.y, az = bv.z, aw = bv.w;
  #pragma unroll
  for (int ky = 0; ky < 3; ky++) {
    int y = yy + ky - 1;
    if ((unsigned)y >= (unsigned)HH) continue;
    #pragma unroll
    for (int kx = 0; kx < 3; kx++) {
      int x2 = xx + kx - 1;
      if ((unsigned)x2 >= (unsigned)WW) continue;
      const float4 v = *(const float4*)(&x[(((size_t)bb * HH + y) * WW + x2) * CC + c]);
      const float4 wv = *(const float4*)(&w[(ky * 3 + kx) * CC + c]);
      ax = fmaf(v.x, wv.x, ax); ay = fmaf(v.y, wv.y, ay);
      az = fmaf(v.z, wv.z, az); aw = fmaf(v.w, wv.w, aw);
    }
  }
  size_t o = (size_t)pix * CC + c;
  const float4 xv = *(const float4*)(&x[o]);
  float4 r; r.x = xv.x + ax; r.y = xv.y + ay; r.z = xv.z + az; r.w = xv.w + aw;
  *(float4*)(&out[o]) = r;
}

// ---------------- LayerNorm (C=512), one wave per token, bf16 out ----------------
__global__ __launch_bounds__(256) void ln_kernel(
    const float* __restrict__ in, const float* __restrict__ g,
    const float* __restrict__ b, unsigned short* __restrict__ out) {
  int token = (blockIdx.x * 256 + threadIdx.x) >> 6;
  int lane = threadIdx.x & 63;
  const float* row = in + (size_t)token * CC;
  float4 v0 = *(const float4*)(row + lane * 8);
  float4 v1 = *(const float4*)(row + lane * 8 + 4);
  float s = v0.x + v0.y + v0.z + v0.w + v1.x + v1.y + v1.z + v1.w;
  float ss = v0.x*v0.x + v0.y*v0.y + v0.z*v0.z + v0.w*v0.w
           + v1.x*v1.x + v1.y*v1.y + v1.z*v1.z + v1.w*v1.w;
  #pragma unroll
  for (int o = 32; o; o >>= 1) { s += __shfl_xor(s, o, 64); ss += __shfl_xor(ss, o, 64); }
  float mu = s * (1.f / CC);
  float var = ss * (1.f / CC) - mu * mu;
  float rs = rsqrtf(var + 1e-5f);
  float4 g0 = *(const float4*)(&g[lane * 8]);
  float4 g1 = *(const float4*)(&g[lane * 8 + 4]);
  float4 b0 = *(const float4*)(&b[lane * 8]);
  float4 b1 = *(const float4*)(&b[lane * 8 + 4]);
  unsigned short o8[8];
  o8[0] = f2bf((v0.x - mu) * rs * g0.x + b0.x);
  o8[1] = f2bf((v0.y - mu) * rs * g0.y + b0.y);
  o8[2] = f2bf((v0.z - mu) * rs * g0.z + b0.z);
  o8[3] = f2bf((v0.w - mu) * rs * g0.w + b0.w);
  o8[4] = f2bf((v1.x - mu) * rs * g1.x + b1.x);
  o8[5] = f2bf((v1.y - mu) * rs * g1.y + b1.y);
  o8[6] = f2bf((v1.z - mu) * rs * g1.z + b1.z);
  o8[7] = f2bf((v1.w - mu) * rs * g1.w + b1.w);
  uint4 pk;
  pk.x = (uint32_t)o8[0] | ((uint32_t)o8[1] << 16);
  pk.y = (uint32_t)o8[2] | ((uint32_t)o8[3] << 16);
  pk.z = (uint32_t)o8[4] | ((uint32_t)o8[5] << 16);
  pk.w = (uint32_t)o8[6] | ((uint32_t)o8[7] << 16);
  *(uint4*)(&out[(size_t)token * CC + lane * 8]) = pk;
}

// ---------------- bf16 MFMA GEMM: C = A(MxK) * BT(NxK)^T + bias ----------------
// MODE 0: out bf16 = C + bias            (qkv)
// MODE 1: out f32  = C + bias + res      (proj residual, fc2 residual)
// MODE 2: out bf16 = gelu(C + bias)      (fc1)
#define BM 128
#define BN 128
#define BK 32
#define LDT 48

template <int MODE>
__global__ __launch_bounds__(256) void gemm_kernel(
    const unsigned short* __restrict__ A, const unsigned short* __restrict__ BT,
    const float* __restrict__ bias, const float* __restrict__ res,
    float* __restrict__ outF, unsigned short* __restrict__ outB,
    int M, int N, int K) {
  __shared__ unsigned short As[BM * LDT];
  __shared__ unsigned short Bs[BN * LDT];
  const int bm = blockIdx.y * BM, bn = blockIdx.x * BN;
  const int t = threadIdx.x;
  const int wid = t >> 6, lane = t & 63;
  const int wm = (wid >> 1) * 64, wn = (wid & 1) * 64;
  const int lr = lane & 15, lk = (lane >> 4) * 8;
  f32x4 acc[4][4] = {};
  for (int kt = 0; kt < K; kt += BK) {
    #pragma unroll
    for (int p = 0; p < 2; ++p) {
      int cid = p * 256 + t;
      int row = cid >> 2, c8 = (cid & 3) << 3;
      *(uint4*)(&As[row * LDT + c8]) =
          *(const uint4*)(&A[(size_t)(bm + row) * K + kt + c8]);
      *(uint4*)(&Bs[row * LDT + c8]) =
          *(const uint4*)(&BT[(size_t)(bn + row) * K + kt + c8]);
    }
    __syncthreads();
    bf16x8 af[4], bfr[4];
    #pragma unroll
    for (int i = 0; i < 4; i++)
      af[i] = *(const bf16x8*)(&As[(wm + i * 16 + lr) * LDT + lk]);
    #pragma unroll
    for (int j = 0; j < 4; j++)
      bfr[j] = *(const bf16x8*)(&Bs[(wn + j * 16 + lr) * LDT + lk]);
    #pragma unroll
    for (int i = 0; i < 4; i++)
      #pragma unroll
      for (int j = 0; j < 4; j++)
        acc[i][j] = __builtin_amdgcn_mfma_f32_16x16x32_bf16(af[i], bfr[j], acc[i][j], 0, 0, 0);
    __syncthreads();
  }
  const int orow = (lane >> 4) * 4, ocol = lane & 15;
  #pragma unroll
  for (int i = 0; i < 4; i++) {
    #pragma unroll
    for (int j = 0; j < 4; j++) {
      int gc = bn + wn + j * 16 + ocol;
      float bv = bias[gc];
      #pragma unroll
      for (int r = 0; r < 4; r++) {
        int gr = bm + wm + i * 16 + orow + r;
        size_t off = (size_t)gr * N + gc;
        float v = acc[i][j][r] + bv;
        if (MODE == 0) {
          outB[off] = f2bf(v);
        } else if (MODE == 1) {
          outF[off] = v + res[off];
        } else {
          float u = 0.79788456080286536f * (v + 0.044715f * v * v * v);
          float e = __expf(2.f * u);
          float th = 1.f - 2.f / (e + 1.f);
          outB[off] = f2bf(0.5f * v * (1.f + th));
        }
      }
    }
  }
}

// ---------------- window attention: one block per (window, head) ----------------
__global__ __launch_bounds__(256) void attn_kernel(
    const unsigned short* __restrict__ qkv, unsigned short* __restrict__ out) {
  __shared__ float Qs[49][65], Ks[49][65], Vs[49][65];
  __shared__ float Ps[49][50];
  int w = blockIdx.x, h = blockIdx.y;
  int b = w >> 8, wy = (w >> 4) & 15, wx = w & 15;
  int t = threadIdx.x;
  for (int idx = t; idx < 49 * 64; idx += 256) {
    int r = idx >> 6, dd = idx & 63;
    int l = (wy * 7 + r / 7) * WW + wx * 7 + (r % 7);
    size_t base = ((size_t)(b * LLEN + l)) * 1536 + h * HD + dd;
    Qs[r][dd] = bf2f(qkv[base]);
    Ks[r][dd] = bf2f(qkv[base + 512]);
    Vs[r][dd] = bf2f(qkv[base + 1024]);
  }
  __syncthreads();
  for (int idx = t; idx < 49 * 49; idx += 256) {
    int q = idx / 49, k = idx - q * 49;
    float s = 0.f;
    #pragma unroll
    for (int dd = 0; dd < 64; dd++) s = fmaf(Qs[q][dd], Ks[k][dd], s);
    Ps[q][k] = s * 0.125f;
  }
  __syncthreads();
  if (t < 49) {
    float m = -1e30f;
    for (int k = 0; k < 49; k++) m = fmaxf(m, Ps[t][k]);
    float sum = 0.f;
    for (int k = 0; k < 49; k++) { float e = __expf(Ps[t][k] - m); Ps[t][k] = e; sum += e; }
    float inv = 1.f / sum;
    for (int k = 0; k < 49; k++) Ps[t][k] *= inv;
  }
  __syncthreads();
  for (int idx = t; idx < 49 * 64; idx += 256) {
    int q = idx >> 6, dd = idx & 63;
    float o = 0.f;
    #pragma unroll
    for (int k = 0; k < 49; k++) o = fmaf(Ps[q][k], Vs[k][dd], o);
    int l = (wy * 7 + q / 7) * WW + wx * 7 + (q % 7);
    out[((size_t)(b * LLEN + l)) * CC + h * HD + dd] = f2bf(o);
  }
}

extern "C" void kernel_launch(void* const* d_in, const int* in_sizes, int n_in,
                              void* d_out, int out_size, void* d_ws, size_t ws_size,
                              hipStream_t stream) {
  const float* x      = (const float*)d_in[0];
  const float* cpe0_w = (const float*)d_in[1];
  const float* cpe0_b = (const float*)d_in[2];
  const float* cpe1_w = (const float*)d_in[3];
  const float* cpe1_b = (const float*)d_in[4];
  const float* ln1_g  = (const float*)d_in[5];
  const float* ln1_b  = (const float*)d_in[6];
  const float* ln2_g  = (const float*)d_in[7];
  const float* ln2_b  = (const float*)d_in[8];
  const float* qkv_w  = (const float*)d_in[9];
  const float* qkv_b  = (const float*)d_in[10];
  const float* proj_w = (const float*)d_in[11];
  const float* proj_b = (const float*)d_in[12];
  const float* fc1_w  = (const float*)d_in[13];
  const float* fc1_b  = (const float*)d_in[14];
  const float* fc2_w  = (const float*)d_in[15];
  const float* fc2_b  = (const float*)d_in[16];
  float* out = (float*)d_out;
  char* ws = (char*)d_ws;

  // ws layout (bytes)
  unsigned short* qkvwT  = (unsigned short*)(ws + 0);           // 1536x512 bf16
  unsigned short* projwT = (unsigned short*)(ws + 1572864);     // 512x512
  unsigned short* fc1wT  = (unsigned short*)(ws + 2097152);     // 2048x512
  unsigned short* fc2wT  = (unsigned short*)(ws + 4194304);     // 512x2048
  float*          shortc = (float*)(ws + 6291456);              // 50176x512 f32
  unsigned short* lnb    = (unsigned short*)(ws + 109051904);   // 50176x512 bf16
  unsigned short* qkvb   = (unsigned short*)(ws + 160432128);   // 50176x1536 bf16
  unsigned short* attnb  = (unsigned short*)(ws + 314572800);   // 50176x512 bf16
  unsigned short* gelub  = qkvb;   // overlay: 50176x2048 bf16 == qkv+attn regions
  float* h2 = out;                 // reuse d_out as h2 scratch (fully overwritten)

  wtranspose_kernel<<<(512 * 1536 + 255) / 256, 256, 0, stream>>>(qkv_w, qkvwT, 512, 1536);
  wtranspose_kernel<<<(512 * 512 + 255) / 256, 256, 0, stream>>>(proj_w, projwT, 512, 512);
  wtranspose_kernel<<<(512 * 2048 + 255) / 256, 256, 0, stream>>>(fc1_w, fc1wT, 512, 2048);
  wtranspose_kernel<<<(2048 * 512 + 255) / 256, 256, 0, stream>>>(fc2_w, fc2wT, 2048, 512);

  const int pixblocks = (BB * HH * WW * 128) / 256;   // 25088
  // shortcut = x + dwconv(x)
  cpe_kernel<<<pixblocks, 256, 0, stream>>>(x, cpe0_w, cpe0_b, shortc);
  // ln1
  ln_kernel<<<NTOK / 4, 256, 0, stream>>>(shortc, ln1_g, ln1_b, lnb);
  // qkv = ln1 @ qkv_w + b  -> bf16
  gemm_kernel<0><<<dim3(12, 392), 256, 0, stream>>>(lnb, qkvwT, qkv_b, nullptr,
                                                    nullptr, qkvb, NTOK, 1536, 512);
  // window attention
  attn_kernel<<<dim3(1024, 8), 256, 0, stream>>>(qkvb, attnb);
  // h = shortcut + attn @ proj_w + b (in-place into shortc)
  gemm_kernel<1><<<dim3(4, 392), 256, 0, stream>>>(attnb, projwT, proj_b, shortc,
                                                   shortc, nullptr, NTOK, 512, 512);
  // h2 = h + dwconv(h)   (into d_out)
  cpe_kernel<<<pixblocks, 256, 0, stream>>>(shortc, cpe1_w, cpe1_b, h2);
  // ln2
  ln_kernel<<<NTOK / 4, 256, 0, stream>>>(h2, ln2_g, ln2_b, lnb);
  // fc1 + gelu -> bf16
  gemm_kernel<2><<<dim3(16, 392), 256, 0, stream>>>(lnb, fc1wT, fc1_b, nullptr,
                                                    nullptr, gelub, NTOK, 2048, 512);
  // out = h2 + fc1out @ fc2_w + b
  gemm_kernel<1><<<dim3(4, 392), 256, 0, stream>>>(gelub, fc2wT, fc2_b, h2,
                                                   out, nullptr, NTOK, 512, 2048);
}

// Round 2
// 1003.714 us; speedup vs baseline: 1.1545x; 1.1545x over previous
//
#include <hip/hip_runtime.h>
#include <stdint.h>

#define HH 112
#define WW 112
#define CC 512
#define BB 4
#define LLEN (HH*WW)
#define NTOK (BB*LLEN)   // 50176
#define NHEADS 8
#define HD 64
#define HIDDEN 2048

typedef __bf16 bf16x8 __attribute__((ext_vector_type(8)));
typedef float f32x4 __attribute__((ext_vector_type(4)));

__device__ __forceinline__ unsigned short f2bf(float x) {
  uint32_t u = __float_as_uint(x);
  u += 0x7fffu + ((u >> 16) & 1u);
  return (unsigned short)(u >> 16);
}
__device__ __forceinline__ float bf2f(unsigned short h) {
  return __uint_as_float((uint32_t)h << 16);
}

// async global->LDS, 16B per lane; lds dest must be wave-uniform base
__device__ __forceinline__ void gload16(const void* gptr, void* lptr) {
  __builtin_amdgcn_global_load_lds(
      (const __attribute__((address_space(1))) void*)gptr,
      (__attribute__((address_space(3))) void*)lptr,
      16, 0, 0);
}

// ---------------- weight transpose (K,N) f32 -> (N,K) bf16 ----------------
__global__ __launch_bounds__(256) void wtranspose_kernel(
    const float* __restrict__ w, unsigned short* __restrict__ wt, int K, int N) {
  int idx = blockIdx.x * 256 + threadIdx.x;
  if (idx >= K * N) return;
  int k = idx / N, n = idx - k * N;
  wt[(size_t)n * K + k] = f2bf(w[idx]);
}

// ---------------- depthwise 3x3 conv + bias + residual ----------------
__global__ __launch_bounds__(256) void cpe_kernel(
    const float* __restrict__ x, const float* __restrict__ w,
    const float* __restrict__ bias, float* __restrict__ out) {
  int tid = blockIdx.x * 256 + threadIdx.x;
  int c = (tid & 127) << 2;      // channel chunk of 4
  int pix = tid >> 7;
  int xx = pix % WW; int t2 = pix / WW; int yy = t2 % HH; int bb = t2 / HH;
  float4 bv = *(const float4*)(&bias[c]);
  float ax = bv.x, ay = bv.y, az = bv.z, aw = bv.w;
  #pragma unroll
  for (int ky = 0; ky < 3; ky++) {
    int y = yy + ky - 1;
    if ((unsigned)y >= (unsigned)HH) continue;
    #pragma unroll
    for (int kx = 0; kx < 3; kx++) {
      int x2 = xx + kx - 1;
      if ((unsigned)x2 >= (unsigned)WW) continue;
      const float4 v = *(const float4*)(&x[(((size_t)bb * HH + y) * WW + x2) * CC + c]);
      const float4 wv = *(const float4*)(&w[(ky * 3 + kx) * CC + c]);
      ax = fmaf(v.x, wv.x, ax); ay = fmaf(v.y, wv.y, ay);
      az = fmaf(v.z, wv.z, az); aw = fmaf(v.w, wv.w, aw);
    }
  }
  size_t o = (size_t)pix * CC + c;
  const float4 xv = *(const float4*)(&x[o]);
  float4 r; r.x = xv.x + ax; r.y = xv.y + ay; r.z = xv.z + az; r.w = xv.w + aw;
  *(float4*)(&out[o]) = r;
}

// ---------------- LayerNorm (C=512), one wave per token, bf16 out ----------------
__global__ __launch_bounds__(256) void ln_kernel(
    const float* __restrict__ in, const float* __restrict__ g,
    const float* __restrict__ b, unsigned short* __restrict__ out) {
  int token = (blockIdx.x * 256 + threadIdx.x) >> 6;
  int lane = threadIdx.x & 63;
  const float* row = in + (size_t)token * CC;
  float4 v0 = *(const float4*)(row + lane * 8);
  float4 v1 = *(const float4*)(row + lane * 8 + 4);
  float s = v0.x + v0.y + v0.z + v0.w + v1.x + v1.y + v1.z + v1.w;
  float ss = v0.x*v0.x + v0.y*v0.y + v0.z*v0.z + v0.w*v0.w
           + v1.x*v1.x + v1.y*v1.y + v1.z*v1.z + v1.w*v1.w;
  #pragma unroll
  for (int o = 32; o; o >>= 1) { s += __shfl_xor(s, o, 64); ss += __shfl_xor(ss, o, 64); }
  float mu = s * (1.f / CC);
  float var = ss * (1.f / CC) - mu * mu;
  float rs = rsqrtf(var + 1e-5f);
  float4 g0 = *(const float4*)(&g[lane * 8]);
  float4 g1 = *(const float4*)(&g[lane * 8 + 4]);
  float4 b0 = *(const float4*)(&b[lane * 8]);
  float4 b1 = *(const float4*)(&b[lane * 8 + 4]);
  unsigned short o8[8];
  o8[0] = f2bf((v0.x - mu) * rs * g0.x + b0.x);
  o8[1] = f2bf((v0.y - mu) * rs * g0.y + b0.y);
  o8[2] = f2bf((v0.z - mu) * rs * g0.z + b0.z);
  o8[3] = f2bf((v0.w - mu) * rs * g0.w + b0.w);
  o8[4] = f2bf((v1.x - mu) * rs * g1.x + b1.x);
  o8[5] = f2bf((v1.y - mu) * rs * g1.y + b1.y);
  o8[6] = f2bf((v1.z - mu) * rs * g1.z + b1.z);
  o8[7] = f2bf((v1.w - mu) * rs * g1.w + b1.w);
  uint4 pk;
  pk.x = (uint32_t)o8[0] | ((uint32_t)o8[1] << 16);
  pk.y = (uint32_t)o8[2] | ((uint32_t)o8[3] << 16);
  pk.z = (uint32_t)o8[4] | ((uint32_t)o8[5] << 16);
  pk.w = (uint32_t)o8[6] | ((uint32_t)o8[7] << 16);
  *(uint4*)(&out[(size_t)token * CC + lane * 8]) = pk;
}

// ---------------- bf16 MFMA GEMM (m97 structure): C = A(MxK)*BT(NxK)^T + bias ----
// MODE 0: out bf16 = C + bias            (qkv)
// MODE 1: out f32  = C + bias + res      (proj residual, fc2 residual)
// MODE 2: out bf16 = gelu(C + bias)      (fc1)
#define BM 128
#define BN 128
#define BK 32

template <int MODE>
__global__ __launch_bounds__(256) void gemm_kernel(
    const unsigned short* __restrict__ A, const unsigned short* __restrict__ BT,
    const float* __restrict__ bias, const float* __restrict__ res,
    float* __restrict__ outF, unsigned short* __restrict__ outB,
    int M, int N, int K) {
  __shared__ unsigned short As[BM * BK];
  __shared__ unsigned short Bs[BN * BK];
  // XCD-aware swizzle (all grids divisible by 8)
  int nwg = gridDim.x * gridDim.y;
  int flat = blockIdx.y * gridDim.x + blockIdx.x;
  int swz = (flat & 7) * (nwg >> 3) + (flat >> 3);
  int bx = swz % gridDim.x, by = swz / gridDim.x;
  const int bm = by * BM, bn = bx * BN;
  const int t = threadIdx.x;
  const int wid = t >> 6, lane = t & 63;
  const int wm = (wid >> 1) * 64, wn = (wid & 1) * 64;
  const int lr = lane & 15, lk = (lane >> 4) * 8;
  const int srow = t >> 2, scol = (t & 3) * 8;
  f32x4 acc[4][4] = {};
  for (int kt = 0; kt < K; kt += BK) {
    gload16(&A[(size_t)(bm + srow) * K + kt + scol],       &As[wid * 512]);
    gload16(&A[(size_t)(bm + 64 + srow) * K + kt + scol],  &As[2048 + wid * 512]);
    gload16(&BT[(size_t)(bn + srow) * K + kt + scol],      &Bs[wid * 512]);
    gload16(&BT[(size_t)(bn + 64 + srow) * K + kt + scol], &Bs[2048 + wid * 512]);
    __syncthreads();
    bf16x8 af[4], bfr[4];
    #pragma unroll
    for (int i = 0; i < 4; i++)
      af[i] = *(const bf16x8*)(&As[(wm + i * 16 + lr) * BK + lk]);
    #pragma unroll
    for (int j = 0; j < 4; j++)
      bfr[j] = *(const bf16x8*)(&Bs[(wn + j * 16 + lr) * BK + lk]);
    #pragma unroll
    for (int i = 0; i < 4; i++)
      #pragma unroll
      for (int j = 0; j < 4; j++)
        acc[i][j] = __builtin_amdgcn_mfma_f32_16x16x32_bf16(af[i], bfr[j], acc[i][j], 0, 0, 0);
    __syncthreads();
  }
  const int orow = (lane >> 4) * 4, ocol = lane & 15;
  #pragma unroll
  for (int i = 0; i < 4; i++) {
    #pragma unroll
    for (int j = 0; j < 4; j++) {
      int gc = bn + wn + j * 16 + ocol;
      float bv = bias[gc];
      #pragma unroll
      for (int r = 0; r < 4; r++) {
        int gr = bm + wm + i * 16 + orow + r;
        size_t off = (size_t)gr * N + gc;
        float v = acc[i][j][r] + bv;
        if (MODE == 0) {
          outB[off] = f2bf(v);
        } else if (MODE == 1) {
          outF[off] = v + res[off];
        } else {
          float u = 0.79788456080286536f * (v + 0.044715f * v * v * v);
          float e = __expf(2.f * u);
          float th = 1.f - 2.f / (e + 1.f);
          outB[off] = f2bf(0.5f * v * (1.f + th));
        }
      }
    }
  }
}

// ---------------- MFMA window attention: 1 wave per (window, head) ----------------
#define WNS 68   // LDS row stride (elems): 136B = 8B aligned, odd-dword for banks

__global__ __launch_bounds__(64) void attn_mfma_kernel(
    const unsigned short* __restrict__ qkv, unsigned short* __restrict__ out) {
  __shared__ unsigned short VT[64 * WNS];   // V^T: [d][k]
  __shared__ unsigned short Ps[64 * WNS];   // P:   [q][k]
  const int task = blockIdx.x;
  const int win = task >> 3, h = task & 7;
  const int b = win >> 8, wy = (win >> 4) & 15, wx = win & 15;
  const int lane = threadIdx.x;
  const int lr = lane & 15, g = lane >> 4;

  auto tokof = [&](int r) {
    int rr = r > 48 ? 48 : r;
    int y = rr / 7, x2 = rr - y * 7;
    return (size_t)(b * LLEN + (wy * 7 + y) * WW + wx * 7 + x2);
  };

  // ---- stage V^T (scalar writes: per-instruction row base uniform -> conflict-free)
  {
    size_t vbase = tokof(lane) * 1536 + h * 64 + 1024;
    bool valid = lane <= 48;
    #pragma unroll
    for (int c = 0; c < 8; c++) {
      uint4 v = *(const uint4*)(&qkv[vbase + c * 8]);
      const unsigned short* pv = (const unsigned short*)&v;
      #pragma unroll
      for (int e = 0; e < 8; e++)
        VT[(c * 8 + e) * WNS + lane] = valid ? pv[e] : (unsigned short)0;
    }
  }

  // ---- Q,K fragments straight from global (A/B frag rows = lr + 16*tile)
  size_t tok[4];
  #pragma unroll
  for (int i2 = 0; i2 < 4; i2++) tok[i2] = tokof(i2 * 16 + lr);
  bf16x8 Qf[4][2], Kf[4][2];
  #pragma unroll
  for (int i2 = 0; i2 < 4; i2++) {
    size_t base = tok[i2] * 1536 + h * 64 + g * 8;
    #pragma unroll
    for (int ks = 0; ks < 2; ks++) {
      Qf[i2][ks] = *(const bf16x8*)(&qkv[base + ks * 32]);
      Kf[i2][ks] = *(const bf16x8*)(&qkv[base + 512 + ks * 32]);
    }
  }

  // ---- S^T = K·Q^T : acc[i=k-tile][j=q-tile], C row = k, col = q
  f32x4 acc[4][4] = {};
  #pragma unroll
  for (int ks = 0; ks < 2; ks++)
    #pragma unroll
    for (int i2 = 0; i2 < 4; i2++)
      #pragma unroll
      for (int j = 0; j < 4; j++)
        acc[i2][j] = __builtin_amdgcn_mfma_f32_16x16x32_bf16(Kf[i2][ks], Qf[j][ks], acc[i2][j], 0, 0, 0);

  // ---- softmax over k (row axis of S^T): in-reg over 16 vals + shfl 16,32
  #pragma unroll
  for (int j = 0; j < 4; j++) {
    float mx = -1e30f;
    #pragma unroll
    for (int i2 = 0; i2 < 4; i2++)
      #pragma unroll
      for (int r = 0; r < 4; r++) {
        int k = 16 * i2 + 4 * g + r;
        mx = fmaxf(mx, (k <= 48) ? acc[i2][j][r] : -1e30f);
      }
    mx = fmaxf(mx, __shfl_xor(mx, 16, 64));
    mx = fmaxf(mx, __shfl_xor(mx, 32, 64));
    float p[4][4];
    float sum = 0.f;
    #pragma unroll
    for (int i2 = 0; i2 < 4; i2++)
      #pragma unroll
      for (int r = 0; r < 4; r++) {
        int k = 16 * i2 + 4 * g + r;
        float e = (k <= 48) ? __expf(0.125f * (acc[i2][j][r] - mx)) : 0.f;
        p[i2][r] = e; sum += e;
      }
    sum += __shfl_xor(sum, 16, 64);
    sum += __shfl_xor(sum, 32, 64);
    float inv = 1.f / sum;
    int q = 16 * j + lr;
    #pragma unroll
    for (int i2 = 0; i2 < 4; i2++) {
      uint2 w;
      w.x = (uint32_t)f2bf(p[i2][0] * inv) | ((uint32_t)f2bf(p[i2][1] * inv) << 16);
      w.y = (uint32_t)f2bf(p[i2][2] * inv) | ((uint32_t)f2bf(p[i2][3] * inv) << 16);
      *(uint2*)(&Ps[q * WNS + 16 * i2 + 4 * g]) = w;
    }
  }

  __syncthreads();   // VT + Ps writes -> reads fence

  // ---- O = P·V : A = P[q][k], B^T = VT[d][k]; o[i=q-tile][j=d-tile]
  f32x4 o[4][4] = {};
  #pragma unroll
  for (int ks = 0; ks < 2; ks++) {
    bf16x8 Pf[4], Vf[4];
    #pragma unroll
    for (int i2 = 0; i2 < 4; i2++) {
      int base = (16 * i2 + lr) * WNS + ks * 32 + g * 8;
      uint2 lo = *(const uint2*)(&Ps[base]);
      uint2 hi = *(const uint2*)(&Ps[base + 4]);
      uint4 u; u.x = lo.x; u.y = lo.y; u.z = hi.x; u.w = hi.y;
      Pf[i2] = *(bf16x8*)&u;
    }
    #pragma unroll
    for (int j = 0; j < 4; j++) {
      int base = (16 * j + lr) * WNS + ks * 32 + g * 8;
      uint2 lo = *(const uint2*)(&VT[base]);
      uint2 hi = *(const uint2*)(&VT[base + 4]);
      uint4 u; u.x = lo.x; u.y = lo.y; u.z = hi.x; u.w = hi.y;
      Vf[j] = *(bf16x8*)&u;
    }
    #pragma unroll
    for (int i2 = 0; i2 < 4; i2++)
      #pragma unroll
      for (int j = 0; j < 4; j++)
        o[i2][j] = __builtin_amdgcn_mfma_f32_16x16x32_bf16(Pf[i2], Vf[j], o[i2][j], 0, 0, 0);
  }

  // ---- store O rows q<49
  #pragma unroll
  for (int i2 = 0; i2 < 4; i2++)
    #pragma unroll
    for (int r = 0; r < 4; r++) {
      int q = 16 * i2 + 4 * g + r;
      if (q <= 48) {
        size_t obase = tokof(q) * 512 + h * 64 + lr;
        #pragma unroll
        for (int j = 0; j < 4; j++)
          out[obase + 16 * j] = f2bf(o[i2][j][r]);
      }
    }
}

extern "C" void kernel_launch(void* const* d_in, const int* in_sizes, int n_in,
                              void* d_out, int out_size, void* d_ws, size_t ws_size,
                              hipStream_t stream) {
  const float* x      = (const float*)d_in[0];
  const float* cpe0_w = (const float*)d_in[1];
  const float* cpe0_b = (const float*)d_in[2];
  const float* cpe1_w = (const float*)d_in[3];
  const float* cpe1_b = (const float*)d_in[4];
  const float* ln1_g  = (const float*)d_in[5];
  const float* ln1_b  = (const float*)d_in[6];
  const float* ln2_g  = (const float*)d_in[7];
  const float* ln2_b  = (const float*)d_in[8];
  const float* qkv_w  = (const float*)d_in[9];
  const float* qkv_b  = (const float*)d_in[10];
  const float* proj_w = (const float*)d_in[11];
  const float* proj_b = (const float*)d_in[12];
  const float* fc1_w  = (const float*)d_in[13];
  const float* fc1_b  = (const float*)d_in[14];
  const float* fc2_w  = (const float*)d_in[15];
  const float* fc2_b  = (const float*)d_in[16];
  float* out = (float*)d_out;
  char* ws = (char*)d_ws;

  unsigned short* qkvwT  = (unsigned short*)(ws + 0);           // 1536x512 bf16
  unsigned short* projwT = (unsigned short*)(ws + 1572864);     // 512x512
  unsigned short* fc1wT  = (unsigned short*)(ws + 2097152);     // 2048x512
  unsigned short* fc2wT  = (unsigned short*)(ws + 4194304);     // 512x2048
  float*          shortc = (float*)(ws + 6291456);              // 50176x512 f32
  unsigned short* lnb    = (unsigned short*)(ws + 109051904);   // 50176x512 bf16
  unsigned short* qkvb   = (unsigned short*)(ws + 160432128);   // 50176x1536 bf16
  unsigned short* attnb  = (unsigned short*)(ws + 314572800);   // 50176x512 bf16
  unsigned short* gelub  = qkvb;   // overlay: 50176x2048 bf16
  float* h2 = out;                 // reuse d_out as h2 scratch

  wtranspose_kernel<<<(512 * 1536 + 255) / 256, 256, 0, stream>>>(qkv_w, qkvwT, 512, 1536);
  wtranspose_kernel<<<(512 * 512 + 255) / 256, 256, 0, stream>>>(proj_w, projwT, 512, 512);
  wtranspose_kernel<<<(512 * 2048 + 255) / 256, 256, 0, stream>>>(fc1_w, fc1wT, 512, 2048);
  wtranspose_kernel<<<(2048 * 512 + 255) / 256, 256, 0, stream>>>(fc2_w, fc2wT, 2048, 512);

  const int pixblocks = (BB * HH * WW * 128) / 256;   // 25088
  cpe_kernel<<<pixblocks, 256, 0, stream>>>(x, cpe0_w, cpe0_b, shortc);
  ln_kernel<<<NTOK / 4, 256, 0, stream>>>(shortc, ln1_g, ln1_b, lnb);
  gemm_kernel<0><<<dim3(12, 392), 256, 0, stream>>>(lnb, qkvwT, qkv_b, nullptr,
                                                    nullptr, qkvb, NTOK, 1536, 512);
  attn_mfma_kernel<<<8192, 64, 0, stream>>>(qkvb, attnb);
  gemm_kernel<1><<<dim3(4, 392), 256, 0, stream>>>(attnb, projwT, proj_b, shortc,
                                                   shortc, nullptr, NTOK, 512, 512);
  cpe_kernel<<<pixblocks, 256, 0, stream>>>(shortc, cpe1_w, cpe1_b, h2);
  ln_kernel<<<NTOK / 4, 256, 0, stream>>>(h2, ln2_g, ln2_b, lnb);
  gemm_kernel<2><<<dim3(16, 392), 256, 0, stream>>>(lnb, fc1wT, fc1_b, nullptr,
                                                    nullptr, gelub, NTOK, 2048, 512);
  gemm_kernel<1><<<dim3(4, 392), 256, 0, stream>>>(gelub, fc2wT, fc2_b, h2,
                                                   out, nullptr, NTOK, 512, 2048);
}

// Round 3
// 892.228 us; speedup vs baseline: 1.2987x; 1.1250x over previous
//
#include <hip/hip_runtime.h>
#include <stdint.h>

#define HH 112
#define WW 112
#define CC 512
#define BB 4
#define LLEN (HH*WW)
#define NTOK (BB*LLEN)   // 50176
#define NHEADS 8
#define HD 64
#define HIDDEN 2048

typedef __bf16 bf16x8 __attribute__((ext_vector_type(8)));
typedef float f32x4 __attribute__((ext_vector_type(4)));

__device__ __forceinline__ unsigned short f2bf(float x) {
  uint32_t u = __float_as_uint(x);
  u += 0x7fffu + ((u >> 16) & 1u);
  return (unsigned short)(u >> 16);
}
__device__ __forceinline__ float bf2f(unsigned short h) {
  return __uint_as_float((uint32_t)h << 16);
}

// async global->LDS, 16B per lane; lds dest must be wave-uniform base
__device__ __forceinline__ void gload16(const void* gptr, void* lptr) {
  __builtin_amdgcn_global_load_lds(
      (const __attribute__((address_space(1))) void*)gptr,
      (__attribute__((address_space(3))) void*)lptr,
      16, 0, 0);
}

// ---------------- weight transpose (K,N) f32 -> (N,K) bf16 ----------------
__global__ __launch_bounds__(256) void wtranspose_kernel(
    const float* __restrict__ w, unsigned short* __restrict__ wt, int K, int N) {
  int idx = blockIdx.x * 256 + threadIdx.x;
  if (idx >= K * N) return;
  int k = idx / N, n = idx - k * N;
  wt[(size_t)n * K + k] = f2bf(w[idx]);
}

// ---------------- depthwise 3x3 conv + bias + residual ----------------
__global__ __launch_bounds__(256) void cpe_kernel(
    const float* __restrict__ x, const float* __restrict__ w,
    const float* __restrict__ bias, float* __restrict__ out) {
  int tid = blockIdx.x * 256 + threadIdx.x;
  int c = (tid & 127) << 2;      // channel chunk of 4
  int pix = tid >> 7;
  int xx = pix % WW; int t2 = pix / WW; int yy = t2 % HH; int bb = t2 / HH;
  float4 bv = *(const float4*)(&bias[c]);
  float ax = bv.x, ay = bv.y, az = bv.z, aw = bv.w;
  #pragma unroll
  for (int ky = 0; ky < 3; ky++) {
    int y = yy + ky - 1;
    if ((unsigned)y >= (unsigned)HH) continue;
    #pragma unroll
    for (int kx = 0; kx < 3; kx++) {
      int x2 = xx + kx - 1;
      if ((unsigned)x2 >= (unsigned)WW) continue;
      const float4 v = *(const float4*)(&x[(((size_t)bb * HH + y) * WW + x2) * CC + c]);
      const float4 wv = *(const float4*)(&w[(ky * 3 + kx) * CC + c]);
      ax = fmaf(v.x, wv.x, ax); ay = fmaf(v.y, wv.y, ay);
      az = fmaf(v.z, wv.z, az); aw = fmaf(v.w, wv.w, aw);
    }
  }
  size_t o = (size_t)pix * CC + c;
  const float4 xv = *(const float4*)(&x[o]);
  float4 r; r.x = xv.x + ax; r.y = xv.y + ay; r.z = xv.z + az; r.w = xv.w + aw;
  *(float4*)(&out[o]) = r;
}

// ---------------- LayerNorm (C=512), one wave per token, bf16 out ----------------
__global__ __launch_bounds__(256) void ln_kernel(
    const float* __restrict__ in, const float* __restrict__ g,
    const float* __restrict__ b, unsigned short* __restrict__ out) {
  int token = (blockIdx.x * 256 + threadIdx.x) >> 6;
  int lane = threadIdx.x & 63;
  const float* row = in + (size_t)token * CC;
  float4 v0 = *(const float4*)(row + lane * 8);
  float4 v1 = *(const float4*)(row + lane * 8 + 4);
  float s = v0.x + v0.y + v0.z + v0.w + v1.x + v1.y + v1.z + v1.w;
  float ss = v0.x*v0.x + v0.y*v0.y + v0.z*v0.z + v0.w*v0.w
           + v1.x*v1.x + v1.y*v1.y + v1.z*v1.z + v1.w*v1.w;
  #pragma unroll
  for (int o = 32; o; o >>= 1) { s += __shfl_xor(s, o, 64); ss += __shfl_xor(ss, o, 64); }
  float mu = s * (1.f / CC);
  float var = ss * (1.f / CC) - mu * mu;
  float rs = rsqrtf(var + 1e-5f);
  float4 g0 = *(const float4*)(&g[lane * 8]);
  float4 g1 = *(const float4*)(&g[lane * 8 + 4]);
  float4 b0 = *(const float4*)(&b[lane * 8]);
  float4 b1 = *(const float4*)(&b[lane * 8 + 4]);
  unsigned short o8[8];
  o8[0] = f2bf((v0.x - mu) * rs * g0.x + b0.x);
  o8[1] = f2bf((v0.y - mu) * rs * g0.y + b0.y);
  o8[2] = f2bf((v0.z - mu) * rs * g0.z + b0.z);
  o8[3] = f2bf((v0.w - mu) * rs * g0.w + b0.w);
  o8[4] = f2bf((v1.x - mu) * rs * g1.x + b1.x);
  o8[5] = f2bf((v1.y - mu) * rs * g1.y + b1.y);
  o8[6] = f2bf((v1.z - mu) * rs * g1.z + b1.z);
  o8[7] = f2bf((v1.w - mu) * rs * g1.w + b1.w);
  uint4 pk;
  pk.x = (uint32_t)o8[0] | ((uint32_t)o8[1] << 16);
  pk.y = (uint32_t)o8[2] | ((uint32_t)o8[3] << 16);
  pk.z = (uint32_t)o8[4] | ((uint32_t)o8[5] << 16);
  pk.w = (uint32_t)o8[6] | ((uint32_t)o8[7] << 16);
  *(uint4*)(&out[(size_t)token * CC + lane * 8]) = pk;
}

// ---------------- bf16 MFMA GEMM, 2-phase double-buffered (T3-minimal) ----------
// MODE 0: out bf16 = C + bias            (qkv)
// MODE 1: out f32  = C + bias + res      (proj residual, fc2 residual)
// MODE 2: out bf16 = gelu(C + bias)      (fc1)
#define BM 128
#define BN 128
#define BK 32

template <int MODE>
__global__ __launch_bounds__(256) void gemm_kernel(
    const unsigned short* __restrict__ A, const unsigned short* __restrict__ BT,
    const float* __restrict__ bias, const float* __restrict__ res,
    float* __restrict__ outF, unsigned short* __restrict__ outB,
    int M, int N, int K) {
  __shared__ unsigned short As[2][BM * BK];
  __shared__ unsigned short Bs[2][BN * BK];
  // XCD-aware swizzle (all grids divisible by 8)
  int nwg = gridDim.x * gridDim.y;
  int flat = blockIdx.y * gridDim.x + blockIdx.x;
  int swz = (flat & 7) * (nwg >> 3) + (flat >> 3);
  int bx = swz % gridDim.x, by = swz / gridDim.x;
  const int bm = by * BM, bn = bx * BN;
  const int t = threadIdx.x;
  const int wid = t >> 6, lane = t & 63;
  const int wm = (wid >> 1) * 64, wn = (wid & 1) * 64;
  const int lr = lane & 15, lk = (lane >> 4) * 8;
  const int srow = t >> 2, scol = (t & 3) * 8;
  const size_t arow0 = (size_t)(bm + srow) * K + scol;
  const size_t arow1 = (size_t)(bm + 64 + srow) * K + scol;
  const size_t brow0 = (size_t)(bn + srow) * K + scol;
  const size_t brow1 = (size_t)(bn + 64 + srow) * K + scol;

  f32x4 acc[4][4] = {};

  // prologue: stage tile 0 into buf 0
  gload16(&A[arow0],  &As[0][wid * 512]);
  gload16(&A[arow1],  &As[0][2048 + wid * 512]);
  gload16(&BT[brow0], &Bs[0][wid * 512]);
  gload16(&BT[brow1], &Bs[0][2048 + wid * 512]);
  __syncthreads();

  int cur = 0;
  const int nt = K / BK;
  for (int tile = 0; tile < nt - 1; ++tile) {
    // issue prefetch of tile+1 into buf cur^1 FIRST (stays in flight under compute)
    int kt = (tile + 1) * BK;
    gload16(&A[arow0 + kt],  &As[cur ^ 1][wid * 512]);
    gload16(&A[arow1 + kt],  &As[cur ^ 1][2048 + wid * 512]);
    gload16(&BT[brow0 + kt], &Bs[cur ^ 1][wid * 512]);
    gload16(&BT[brow1 + kt], &Bs[cur ^ 1][2048 + wid * 512]);
    // compute on buf cur
    bf16x8 af[4], bfr[4];
    #pragma unroll
    for (int i = 0; i < 4; i++)
      af[i] = *(const bf16x8*)(&As[cur][(wm + i * 16 + lr) * BK + lk]);
    #pragma unroll
    for (int j = 0; j < 4; j++)
      bfr[j] = *(const bf16x8*)(&Bs[cur][(wn + j * 16 + lr) * BK + lk]);
    #pragma unroll
    for (int i = 0; i < 4; i++)
      #pragma unroll
      for (int j = 0; j < 4; j++)
        acc[i][j] = __builtin_amdgcn_mfma_f32_16x16x32_bf16(af[i], bfr[j], acc[i][j], 0, 0, 0);
    __syncthreads();   // drains vmcnt(0) for prefetch (hidden under compute above)
    cur ^= 1;
  }
  // epilogue tile
  {
    bf16x8 af[4], bfr[4];
    #pragma unroll
    for (int i = 0; i < 4; i++)
      af[i] = *(const bf16x8*)(&As[cur][(wm + i * 16 + lr) * BK + lk]);
    #pragma unroll
    for (int j = 0; j < 4; j++)
      bfr[j] = *(const bf16x8*)(&Bs[cur][(wn + j * 16 + lr) * BK + lk]);
    #pragma unroll
    for (int i = 0; i < 4; i++)
      #pragma unroll
      for (int j = 0; j < 4; j++)
        acc[i][j] = __builtin_amdgcn_mfma_f32_16x16x32_bf16(af[i], bfr[j], acc[i][j], 0, 0, 0);
  }

  const int orow = (lane >> 4) * 4, ocol = lane & 15;
  #pragma unroll
  for (int i = 0; i < 4; i++) {
    #pragma unroll
    for (int j = 0; j < 4; j++) {
      int gc = bn + wn + j * 16 + ocol;
      float bv = bias[gc];
      #pragma unroll
      for (int r = 0; r < 4; r++) {
        int gr = bm + wm + i * 16 + orow + r;
        size_t off = (size_t)gr * N + gc;
        float v = acc[i][j][r] + bv;
        if (MODE == 0) {
          outB[off] = f2bf(v);
        } else if (MODE == 1) {
          outF[off] = v + res[off];
        } else {
          float u = 0.79788456080286536f * (v + 0.044715f * v * v * v);
          float e = __expf(2.f * u);
          float th = 1.f - 2.f / (e + 1.f);
          outB[off] = f2bf(0.5f * v * (1.f + th));
        }
      }
    }
  }
}

// ---------------- MFMA window attention: 1 wave per (window, head) ----------------
#define WNS 68   // LDS row stride (elems): 136B = 8B aligned, odd-dword for banks

__global__ __launch_bounds__(64) void attn_mfma_kernel(
    const unsigned short* __restrict__ qkv, unsigned short* __restrict__ out) {
  __shared__ unsigned short VT[64 * WNS];   // V^T: [d][k]
  __shared__ unsigned short Ps[64 * WNS];   // P:   [q][k]
  const int task = blockIdx.x;
  const int win = task >> 3, h = task & 7;
  const int b = win >> 8, wy = (win >> 4) & 15, wx = win & 15;
  const int lane = threadIdx.x;
  const int lr = lane & 15, g = lane >> 4;

  auto tokof = [&](int r) {
    int rr = r > 48 ? 48 : r;
    int y = rr / 7, x2 = rr - y * 7;
    return (size_t)(b * LLEN + (wy * 7 + y) * WW + wx * 7 + x2);
  };

  // ---- stage V^T (scalar writes: per-instruction row base uniform -> conflict-free)
  {
    size_t vbase = tokof(lane) * 1536 + h * 64 + 1024;
    bool valid = lane <= 48;
    #pragma unroll
    for (int c = 0; c < 8; c++) {
      uint4 v = *(const uint4*)(&qkv[vbase + c * 8]);
      const unsigned short* pv = (const unsigned short*)&v;
      #pragma unroll
      for (int e = 0; e < 8; e++)
        VT[(c * 8 + e) * WNS + lane] = valid ? pv[e] : (unsigned short)0;
    }
  }

  // ---- Q,K fragments straight from global (A/B frag rows = lr + 16*tile)
  size_t tok[4];
  #pragma unroll
  for (int i2 = 0; i2 < 4; i2++) tok[i2] = tokof(i2 * 16 + lr);
  bf16x8 Qf[4][2], Kf[4][2];
  #pragma unroll
  for (int i2 = 0; i2 < 4; i2++) {
    size_t base = tok[i2] * 1536 + h * 64 + g * 8;
    #pragma unroll
    for (int ks = 0; ks < 2; ks++) {
      Qf[i2][ks] = *(const bf16x8*)(&qkv[base + ks * 32]);
      Kf[i2][ks] = *(const bf16x8*)(&qkv[base + 512 + ks * 32]);
    }
  }

  // ---- S^T = K·Q^T : acc[i=k-tile][j=q-tile], C row = k, col = q
  f32x4 acc[4][4] = {};
  #pragma unroll
  for (int ks = 0; ks < 2; ks++)
    #pragma unroll
    for (int i2 = 0; i2 < 4; i2++)
      #pragma unroll
      for (int j = 0; j < 4; j++)
        acc[i2][j] = __builtin_amdgcn_mfma_f32_16x16x32_bf16(Kf[i2][ks], Qf[j][ks], acc[i2][j], 0, 0, 0);

  // ---- softmax over k (row axis of S^T): in-reg over 16 vals + shfl 16,32
  #pragma unroll
  for (int j = 0; j < 4; j++) {
    float mx = -1e30f;
    #pragma unroll
    for (int i2 = 0; i2 < 4; i2++)
      #pragma unroll
      for (int r = 0; r < 4; r++) {
        int k = 16 * i2 + 4 * g + r;
        mx = fmaxf(mx, (k <= 48) ? acc[i2][j][r] : -1e30f);
      }
    mx = fmaxf(mx, __shfl_xor(mx, 16, 64));
    mx = fmaxf(mx, __shfl_xor(mx, 32, 64));
    float p[4][4];
    float sum = 0.f;
    #pragma unroll
    for (int i2 = 0; i2 < 4; i2++)
      #pragma unroll
      for (int r = 0; r < 4; r++) {
        int k = 16 * i2 + 4 * g + r;
        float e = (k <= 48) ? __expf(0.125f * (acc[i2][j][r] - mx)) : 0.f;
        p[i2][r] = e; sum += e;
      }
    sum += __shfl_xor(sum, 16, 64);
    sum += __shfl_xor(sum, 32, 64);
    float inv = 1.f / sum;
    int q = 16 * j + lr;
    #pragma unroll
    for (int i2 = 0; i2 < 4; i2++) {
      uint2 w;
      w.x = (uint32_t)f2bf(p[i2][0] * inv) | ((uint32_t)f2bf(p[i2][1] * inv) << 16);
      w.y = (uint32_t)f2bf(p[i2][2] * inv) | ((uint32_t)f2bf(p[i2][3] * inv) << 16);
      *(uint2*)(&Ps[q * WNS + 16 * i2 + 4 * g]) = w;
    }
  }

  __syncthreads();   // VT + Ps writes -> reads fence

  // ---- O = P·V : A = P[q][k], B^T = VT[d][k]; o[i=q-tile][j=d-tile]
  f32x4 o[4][4] = {};
  #pragma unroll
  for (int ks = 0; ks < 2; ks++) {
    bf16x8 Pf[4], Vf[4];
    #pragma unroll
    for (int i2 = 0; i2 < 4; i2++) {
      int base = (16 * i2 + lr) * WNS + ks * 32 + g * 8;
      uint2 lo = *(const uint2*)(&Ps[base]);
      uint2 hi = *(const uint2*)(&Ps[base + 4]);
      uint4 u; u.x = lo.x; u.y = lo.y; u.z = hi.x; u.w = hi.y;
      Pf[i2] = *(bf16x8*)&u;
    }
    #pragma unroll
    for (int j = 0; j < 4; j++) {
      int base = (16 * j + lr) * WNS + ks * 32 + g * 8;
      uint2 lo = *(const uint2*)(&VT[base]);
      uint2 hi = *(const uint2*)(&VT[base + 4]);
      uint4 u; u.x = lo.x; u.y = lo.y; u.z = hi.x; u.w = hi.y;
      Vf[j] = *(bf16x8*)&u;
    }
    #pragma unroll
    for (int i2 = 0; i2 < 4; i2++)
      #pragma unroll
      for (int j = 0; j < 4; j++)
        o[i2][j] = __builtin_amdgcn_mfma_f32_16x16x32_bf16(Pf[i2], Vf[j], o[i2][j], 0, 0, 0);
  }

  // ---- store O rows q<49
  #pragma unroll
  for (int i2 = 0; i2 < 4; i2++)
    #pragma unroll
    for (int r = 0; r < 4; r++) {
      int q = 16 * i2 + 4 * g + r;
      if (q <= 48) {
        size_t obase = tokof(q) * 512 + h * 64 + lr;
        #pragma unroll
        for (int j = 0; j < 4; j++)
          out[obase + 16 * j] = f2bf(o[i2][j][r]);
      }
    }
}

extern "C" void kernel_launch(void* const* d_in, const int* in_sizes, int n_in,
                              void* d_out, int out_size, void* d_ws, size_t ws_size,
                              hipStream_t stream) {
  const float* x      = (const float*)d_in[0];
  const float* cpe0_w = (const float*)d_in[1];
  const float* cpe0_b = (const float*)d_in[2];
  const float* cpe1_w = (const float*)d_in[3];
  const float* cpe1_b = (const float*)d_in[4];
  const float* ln1_g  = (const float*)d_in[5];
  const float* ln1_b  = (const float*)d_in[6];
  const float* ln2_g  = (const float*)d_in[7];
  const float* ln2_b  = (const float*)d_in[8];
  const float* qkv_w  = (const float*)d_in[9];
  const float* qkv_b  = (const float*)d_in[10];
  const float* proj_w = (const float*)d_in[11];
  const float* proj_b = (const float*)d_in[12];
  const float* fc1_w  = (const float*)d_in[13];
  const float* fc1_b  = (const float*)d_in[14];
  const float* fc2_w  = (const float*)d_in[15];
  const float* fc2_b  = (const float*)d_in[16];
  float* out = (float*)d_out;
  char* ws = (char*)d_ws;

  unsigned short* qkvwT  = (unsigned short*)(ws + 0);           // 1536x512 bf16
  unsigned short* projwT = (unsigned short*)(ws + 1572864);     // 512x512
  unsigned short* fc1wT  = (unsigned short*)(ws + 2097152);     // 2048x512
  unsigned short* fc2wT  = (unsigned short*)(ws + 4194304);     // 512x2048
  float*          shortc = (float*)(ws + 6291456);              // 50176x512 f32
  unsigned short* lnb    = (unsigned short*)(ws + 109051904);   // 50176x512 bf16
  unsigned short* qkvb   = (unsigned short*)(ws + 160432128);   // 50176x1536 bf16
  unsigned short* attnb  = (unsigned short*)(ws + 314572800);   // 50176x512 bf16
  unsigned short* gelub  = qkvb;   // overlay: 50176x2048 bf16
  float* h2 = out;                 // reuse d_out as h2 scratch

  wtranspose_kernel<<<(512 * 1536 + 255) / 256, 256, 0, stream>>>(qkv_w, qkvwT, 512, 1536);
  wtranspose_kernel<<<(512 * 512 + 255) / 256, 256, 0, stream>>>(proj_w, projwT, 512, 512);
  wtranspose_kernel<<<(512 * 2048 + 255) / 256, 256, 0, stream>>>(fc1_w, fc1wT, 512, 2048);
  wtranspose_kernel<<<(2048 * 512 + 255) / 256, 256, 0, stream>>>(fc2_w, fc2wT, 2048, 512);

  const int pixblocks = (BB * HH * WW * 128) / 256;   // 25088
  cpe_kernel<<<pixblocks, 256, 0, stream>>>(x, cpe0_w, cpe0_b, shortc);
  ln_kernel<<<NTOK / 4, 256, 0, stream>>>(shortc, ln1_g, ln1_b, lnb);
  gemm_kernel<0><<<dim3(12, 392), 256, 0, stream>>>(lnb, qkvwT, qkv_b, nullptr,
                                                    nullptr, qkvb, NTOK, 1536, 512);
  attn_mfma_kernel<<<8192, 64, 0, stream>>>(qkvb, attnb);
  gemm_kernel<1><<<dim3(4, 392), 256, 0, stream>>>(attnb, projwT, proj_b, shortc,
                                                   shortc, nullptr, NTOK, 512, 512);
  cpe_kernel<<<pixblocks, 256, 0, stream>>>(shortc, cpe1_w, cpe1_b, h2);
  ln_kernel<<<NTOK / 4, 256, 0, stream>>>(h2, ln2_g, ln2_b, lnb);
  gemm_kernel<2><<<dim3(16, 392), 256, 0, stream>>>(lnb, fc1wT, fc1_b, nullptr,
                                                    nullptr, gelub, NTOK, 2048, 512);
  gemm_kernel<1><<<dim3(4, 392), 256, 0, stream>>>(gelub, fc2wT, fc2_b, h2,
                                                   out, nullptr, NTOK, 512, 2048);
}

// Round 4
// 813.567 us; speedup vs baseline: 1.4243x; 1.0967x over previous
//
#include <hip/hip_runtime.h>
#include <stdint.h>

#define HH 112
#define WW 112
#define CC 512
#define BB 4
#define LLEN (HH*WW)
#define NTOK (BB*LLEN)   // 50176
#define NHEADS 8
#define HD 64
#define HIDDEN 2048

typedef __bf16 bf16x8 __attribute__((ext_vector_type(8)));
typedef float f32x4 __attribute__((ext_vector_type(4)));

__device__ __forceinline__ unsigned short f2bf(float x) {
  uint32_t u = __float_as_uint(x);
  u += 0x7fffu + ((u >> 16) & 1u);
  return (unsigned short)(u >> 16);
}
__device__ __forceinline__ float bf2f(unsigned short h) {
  return __uint_as_float((uint32_t)h << 16);
}

// async global->LDS, 16B per lane; lds dest must be wave-uniform base
__device__ __forceinline__ void gload16(const void* gptr, void* lptr) {
  __builtin_amdgcn_global_load_lds(
      (const __attribute__((address_space(1))) void*)gptr,
      (__attribute__((address_space(3))) void*)lptr,
      16, 0, 0);
}

// ---------------- weight transpose (K,N) f32 -> (N,K) bf16 ----------------
__global__ __launch_bounds__(256) void wtranspose_kernel(
    const float* __restrict__ w, unsigned short* __restrict__ wt, int K, int N) {
  int idx = blockIdx.x * 256 + threadIdx.x;
  if (idx >= K * N) return;
  int k = idx / N, n = idx - k * N;
  wt[(size_t)n * K + k] = f2bf(w[idx]);
}

// ---------------- depthwise 3x3 conv + bias + residual ----------------
__global__ __launch_bounds__(256) void cpe_kernel(
    const float* __restrict__ x, const float* __restrict__ w,
    const float* __restrict__ bias, float* __restrict__ out) {
  int tid = blockIdx.x * 256 + threadIdx.x;
  int c = (tid & 127) << 2;      // channel chunk of 4
  int pix = tid >> 7;
  int xx = pix % WW; int t2 = pix / WW; int yy = t2 % HH; int bb = t2 / HH;
  float4 bv = *(const float4*)(&bias[c]);
  float ax = bv.x, ay = bv.y, az = bv.z, aw = bv.w;
  #pragma unroll
  for (int ky = 0; ky < 3; ky++) {
    int y = yy + ky - 1;
    if ((unsigned)y >= (unsigned)HH) continue;
    #pragma unroll
    for (int kx = 0; kx < 3; kx++) {
      int x2 = xx + kx - 1;
      if ((unsigned)x2 >= (unsigned)WW) continue;
      const float4 v = *(const float4*)(&x[(((size_t)bb * HH + y) * WW + x2) * CC + c]);
      const float4 wv = *(const float4*)(&w[(ky * 3 + kx) * CC + c]);
      ax = fmaf(v.x, wv.x, ax); ay = fmaf(v.y, wv.y, ay);
      az = fmaf(v.z, wv.z, az); aw = fmaf(v.w, wv.w, aw);
    }
  }
  size_t o = (size_t)pix * CC + c;
  const float4 xv = *(const float4*)(&x[o]);
  float4 r; r.x = xv.x + ax; r.y = xv.y + ay; r.z = xv.z + az; r.w = xv.w + aw;
  *(float4*)(&out[o]) = r;
}

// ---------------- LayerNorm (C=512), one wave per token, bf16 out ----------------
__global__ __launch_bounds__(256) void ln_kernel(
    const float* __restrict__ in, const float* __restrict__ g,
    const float* __restrict__ b, unsigned short* __restrict__ out) {
  int token = (blockIdx.x * 256 + threadIdx.x) >> 6;
  int lane = threadIdx.x & 63;
  const float* row = in + (size_t)token * CC;
  float4 v0 = *(const float4*)(row + lane * 8);
  float4 v1 = *(const float4*)(row + lane * 8 + 4);
  float s = v0.x + v0.y + v0.z + v0.w + v1.x + v1.y + v1.z + v1.w;
  float ss = v0.x*v0.x + v0.y*v0.y + v0.z*v0.z + v0.w*v0.w
           + v1.x*v1.x + v1.y*v1.y + v1.z*v1.z + v1.w*v1.w;
  #pragma unroll
  for (int o = 32; o; o >>= 1) { s += __shfl_xor(s, o, 64); ss += __shfl_xor(ss, o, 64); }
  float mu = s * (1.f / CC);
  float var = ss * (1.f / CC) - mu * mu;
  float rs = rsqrtf(var + 1e-5f);
  float4 g0 = *(const float4*)(&g[lane * 8]);
  float4 g1 = *(const float4*)(&g[lane * 8 + 4]);
  float4 b0 = *(const float4*)(&b[lane * 8]);
  float4 b1 = *(const float4*)(&b[lane * 8 + 4]);
  unsigned short o8[8];
  o8[0] = f2bf((v0.x - mu) * rs * g0.x + b0.x);
  o8[1] = f2bf((v0.y - mu) * rs * g0.y + b0.y);
  o8[2] = f2bf((v0.z - mu) * rs * g0.z + b0.z);
  o8[3] = f2bf((v0.w - mu) * rs * g0.w + b0.w);
  o8[4] = f2bf((v1.x - mu) * rs * g1.x + b1.x);
  o8[5] = f2bf((v1.y - mu) * rs * g1.y + b1.y);
  o8[6] = f2bf((v1.z - mu) * rs * g1.z + b1.z);
  o8[7] = f2bf((v1.w - mu) * rs * g1.w + b1.w);
  uint4 pk;
  pk.x = (uint32_t)o8[0] | ((uint32_t)o8[1] << 16);
  pk.y = (uint32_t)o8[2] | ((uint32_t)o8[3] << 16);
  pk.z = (uint32_t)o8[4] | ((uint32_t)o8[5] << 16);
  pk.w = (uint32_t)o8[6] | ((uint32_t)o8[7] << 16);
  *(uint4*)(&out[(size_t)token * CC + lane * 8]) = pk;
}

// ---- bf16 MFMA GEMM: triple-buffered, 2-ahead prefetch, counted vmcnt (T4+T5) ----
// Tile 256x128, BK=32, 512 threads = 8 waves (4 row x 2 col), per-wave out 64x64.
// LDS 72KB -> 2 blocks/CU. One raw barrier per K-tile; vmcnt(3) keeps next tile's
// loads in flight across the barrier (never drain to 0 in main loop).
// MODE 0: out bf16 = C + bias            (qkv)
// MODE 1: out f32  = C + bias + res      (proj residual, fc2 residual)
// MODE 2: out bf16 = gelu(C + bias)      (fc1)
#define BM 256
#define BN 128
#define BK 32

template <int MODE>
__global__ __launch_bounds__(512) void gemm_kernel(
    const unsigned short* __restrict__ A, const unsigned short* __restrict__ BT,
    const float* __restrict__ bias, const float* __restrict__ res,
    float* __restrict__ outF, unsigned short* __restrict__ outB,
    int M, int N, int K) {
  __shared__ unsigned short As[3][BM * BK];   // 3 x 16KB
  __shared__ unsigned short Bs[3][BN * BK];   // 3 x 8KB
  // XCD-aware swizzle (all grids divisible by 8)
  int nwg = gridDim.x * gridDim.y;
  int flat = blockIdx.y * gridDim.x + blockIdx.x;
  int swz = (flat & 7) * (nwg >> 3) + (flat >> 3);
  int bx = swz % gridDim.x, by = swz / gridDim.x;
  const int bm = by * BM, bn = bx * BN;
  const int t = threadIdx.x;
  const int wid = t >> 6, lane = t & 63;
  const int wr = wid >> 1, wc = wid & 1;        // 4x2 wave grid
  const int lr = lane & 15, lk = (lane >> 4) * 8;
  // staging addresses: thread t covers row t>>2, col (t&3)*8
  const size_t arow0 = (size_t)(bm + (t >> 2)) * K + (t & 3) * 8;         // A rows 0-127
  const size_t arow1 = (size_t)(bm + 128 + (t >> 2)) * K + (t & 3) * 8;   // A rows 128-255
  const size_t brow  = (size_t)(bn + (t >> 2)) * K + (t & 3) * 8;         // B rows 0-127
  const int ldsA0 = wid * 512;          // wave-uniform LDS dests (elems)
  const int ldsA1 = 4096 + wid * 512;
  const int ldsB  = wid * 512;

  f32x4 acc[4][4] = {};
  const int nt = K / BK;

  // prologue: stage tiles 0 and 1 (3 loads per thread each)
  gload16(&A[arow0],       &As[0][ldsA0]);
  gload16(&A[arow1],       &As[0][ldsA1]);
  gload16(&BT[brow],       &Bs[0][ldsB]);
  gload16(&A[arow0 + BK],  &As[1][ldsA0]);
  gload16(&A[arow1 + BK],  &As[1][ldsA1]);
  gload16(&BT[brow + BK],  &Bs[1][ldsB]);

  for (int tile = 0; tile < nt - 1; ++tile) {
    // wait for tile's 3 loads (allow tile+1's 3 to stay in flight), then sync.
    asm volatile("s_waitcnt vmcnt(3)" ::: "memory");
    __builtin_amdgcn_s_barrier();
    __builtin_amdgcn_sched_barrier(0);
    const unsigned short* as = As[tile % 3];
    const unsigned short* bs = Bs[tile % 3];
    bf16x8 af[4], bfr[4];
    #pragma unroll
    for (int i = 0; i < 4; i++)
      af[i] = *(const bf16x8*)(&as[(wr * 64 + i * 16 + lr) * BK + lk]);
    #pragma unroll
    for (int j = 0; j < 4; j++)
      bfr[j] = *(const bf16x8*)(&bs[(wc * 64 + j * 16 + lr) * BK + lk]);
    // issue prefetch of tile+2 (overwrites buf[(tile-1)%3]; safe after barrier)
    if (tile + 2 < nt) {
      int kt = (tile + 2) * BK;
      int nb = (tile + 2) % 3;
      gload16(&A[arow0 + kt], &As[nb][ldsA0]);
      gload16(&A[arow1 + kt], &As[nb][ldsA1]);
      gload16(&BT[brow + kt], &Bs[nb][ldsB]);
    }
    __builtin_amdgcn_s_setprio(1);
    #pragma unroll
    for (int i = 0; i < 4; i++)
      #pragma unroll
      for (int j = 0; j < 4; j++)
        acc[i][j] = __builtin_amdgcn_mfma_f32_16x16x32_bf16(af[i], bfr[j], acc[i][j], 0, 0, 0);
    __builtin_amdgcn_s_setprio(0);
  }
  // final tile: drain everything
  {
    asm volatile("s_waitcnt vmcnt(0)" ::: "memory");
    __builtin_amdgcn_s_barrier();
    __builtin_amdgcn_sched_barrier(0);
    const unsigned short* as = As[(nt - 1) % 3];
    const unsigned short* bs = Bs[(nt - 1) % 3];
    bf16x8 af[4], bfr[4];
    #pragma unroll
    for (int i = 0; i < 4; i++)
      af[i] = *(const bf16x8*)(&as[(wr * 64 + i * 16 + lr) * BK + lk]);
    #pragma unroll
    for (int j = 0; j < 4; j++)
      bfr[j] = *(const bf16x8*)(&bs[(wc * 64 + j * 16 + lr) * BK + lk]);
    #pragma unroll
    for (int i = 0; i < 4; i++)
      #pragma unroll
      for (int j = 0; j < 4; j++)
        acc[i][j] = __builtin_amdgcn_mfma_f32_16x16x32_bf16(af[i], bfr[j], acc[i][j], 0, 0, 0);
  }

  const int orow = (lane >> 4) * 4, ocol = lane & 15;
  #pragma unroll
  for (int i = 0; i < 4; i++) {
    #pragma unroll
    for (int j = 0; j < 4; j++) {
      int gc = bn + wc * 64 + j * 16 + ocol;
      float bv = bias[gc];
      #pragma unroll
      for (int r = 0; r < 4; r++) {
        int gr = bm + wr * 64 + i * 16 + orow + r;
        size_t off = (size_t)gr * N + gc;
        float v = acc[i][j][r] + bv;
        if (MODE == 0) {
          outB[off] = f2bf(v);
        } else if (MODE == 1) {
          outF[off] = v + res[off];
        } else {
          float u = 0.79788456080286536f * (v + 0.044715f * v * v * v);
          float e = __expf(2.f * u);
          float th = 1.f - 2.f / (e + 1.f);
          outB[off] = f2bf(0.5f * v * (1.f + th));
        }
      }
    }
  }
}

// ---------------- MFMA window attention: 1 wave per (window, head) ----------------
#define WNS 68   // LDS row stride (elems): 136B = 8B aligned, odd-dword for banks

__global__ __launch_bounds__(64) void attn_mfma_kernel(
    const unsigned short* __restrict__ qkv, unsigned short* __restrict__ out) {
  __shared__ unsigned short VT[64 * WNS];   // V^T: [d][k]
  __shared__ unsigned short Ps[64 * WNS];   // P:   [q][k]
  const int task = blockIdx.x;
  const int win = task >> 3, h = task & 7;
  const int b = win >> 8, wy = (win >> 4) & 15, wx = win & 15;
  const int lane = threadIdx.x;
  const int lr = lane & 15, g = lane >> 4;

  auto tokof = [&](int r) {
    int rr = r > 48 ? 48 : r;
    int y = rr / 7, x2 = rr - y * 7;
    return (size_t)(b * LLEN + (wy * 7 + y) * WW + wx * 7 + x2);
  };

  // ---- stage V^T (scalar writes: per-instruction row base uniform -> conflict-free)
  {
    size_t vbase = tokof(lane) * 1536 + h * 64 + 1024;
    bool valid = lane <= 48;
    #pragma unroll
    for (int c = 0; c < 8; c++) {
      uint4 v = *(const uint4*)(&qkv[vbase + c * 8]);
      const unsigned short* pv = (const unsigned short*)&v;
      #pragma unroll
      for (int e = 0; e < 8; e++)
        VT[(c * 8 + e) * WNS + lane] = valid ? pv[e] : (unsigned short)0;
    }
  }

  // ---- Q,K fragments straight from global (A/B frag rows = lr + 16*tile)
  size_t tok[4];
  #pragma unroll
  for (int i2 = 0; i2 < 4; i2++) tok[i2] = tokof(i2 * 16 + lr);
  bf16x8 Qf[4][2], Kf[4][2];
  #pragma unroll
  for (int i2 = 0; i2 < 4; i2++) {
    size_t base = tok[i2] * 1536 + h * 64 + g * 8;
    #pragma unroll
    for (int ks = 0; ks < 2; ks++) {
      Qf[i2][ks] = *(const bf16x8*)(&qkv[base + ks * 32]);
      Kf[i2][ks] = *(const bf16x8*)(&qkv[base + 512 + ks * 32]);
    }
  }

  // ---- S^T = K·Q^T : acc[i=k-tile][j=q-tile], C row = k, col = q
  f32x4 acc[4][4] = {};
  #pragma unroll
  for (int ks = 0; ks < 2; ks++)
    #pragma unroll
    for (int i2 = 0; i2 < 4; i2++)
      #pragma unroll
      for (int j = 0; j < 4; j++)
        acc[i2][j] = __builtin_amdgcn_mfma_f32_16x16x32_bf16(Kf[i2][ks], Qf[j][ks], acc[i2][j], 0, 0, 0);

  // ---- softmax over k (row axis of S^T): in-reg over 16 vals + shfl 16,32
  #pragma unroll
  for (int j = 0; j < 4; j++) {
    float mx = -1e30f;
    #pragma unroll
    for (int i2 = 0; i2 < 4; i2++)
      #pragma unroll
      for (int r = 0; r < 4; r++) {
        int k = 16 * i2 + 4 * g + r;
        mx = fmaxf(mx, (k <= 48) ? acc[i2][j][r] : -1e30f);
      }
    mx = fmaxf(mx, __shfl_xor(mx, 16, 64));
    mx = fmaxf(mx, __shfl_xor(mx, 32, 64));
    float p[4][4];
    float sum = 0.f;
    #pragma unroll
    for (int i2 = 0; i2 < 4; i2++)
      #pragma unroll
      for (int r = 0; r < 4; r++) {
        int k = 16 * i2 + 4 * g + r;
        float e = (k <= 48) ? __expf(0.125f * (acc[i2][j][r] - mx)) : 0.f;
        p[i2][r] = e; sum += e;
      }
    sum += __shfl_xor(sum, 16, 64);
    sum += __shfl_xor(sum, 32, 64);
    float inv = 1.f / sum;
    int q = 16 * j + lr;
    #pragma unroll
    for (int i2 = 0; i2 < 4; i2++) {
      uint2 w;
      w.x = (uint32_t)f2bf(p[i2][0] * inv) | ((uint32_t)f2bf(p[i2][1] * inv) << 16);
      w.y = (uint32_t)f2bf(p[i2][2] * inv) | ((uint32_t)f2bf(p[i2][3] * inv) << 16);
      *(uint2*)(&Ps[q * WNS + 16 * i2 + 4 * g]) = w;
    }
  }

  __syncthreads();   // VT + Ps writes -> reads fence

  // ---- O = P·V : A = P[q][k], B^T = VT[d][k]; o[i=q-tile][j=d-tile]
  f32x4 o[4][4] = {};
  #pragma unroll
  for (int ks = 0; ks < 2; ks++) {
    bf16x8 Pf[4], Vf[4];
    #pragma unroll
    for (int i2 = 0; i2 < 4; i2++) {
      int base = (16 * i2 + lr) * WNS + ks * 32 + g * 8;
      uint2 lo = *(const uint2*)(&Ps[base]);
      uint2 hi = *(const uint2*)(&Ps[base + 4]);
      uint4 u; u.x = lo.x; u.y = lo.y; u.z = hi.x; u.w = hi.y;
      Pf[i2] = *(bf16x8*)&u;
    }
    #pragma unroll
    for (int j = 0; j < 4; j++) {
      int base = (16 * j + lr) * WNS + ks * 32 + g * 8;
      uint2 lo = *(const uint2*)(&VT[base]);
      uint2 hi = *(const uint2*)(&VT[base + 4]);
      uint4 u; u.x = lo.x; u.y = lo.y; u.z = hi.x; u.w = hi.y;
      Vf[j] = *(bf16x8*)&u;
    }
    #pragma unroll
    for (int i2 = 0; i2 < 4; i2++)
      #pragma unroll
      for (int j = 0; j < 4; j++)
        o[i2][j] = __builtin_amdgcn_mfma_f32_16x16x32_bf16(Pf[i2], Vf[j], o[i2][j], 0, 0, 0);
  }

  // ---- store O rows q<49
  #pragma unroll
  for (int i2 = 0; i2 < 4; i2++)
    #pragma unroll
    for (int r = 0; r < 4; r++) {
      int q = 16 * i2 + 4 * g + r;
      if (q <= 48) {
        size_t obase = tokof(q) * 512 + h * 64 + lr;
        #pragma unroll
        for (int j = 0; j < 4; j++)
          out[obase + 16 * j] = f2bf(o[i2][j][r]);
      }
    }
}

extern "C" void kernel_launch(void* const* d_in, const int* in_sizes, int n_in,
                              void* d_out, int out_size, void* d_ws, size_t ws_size,
                              hipStream_t stream) {
  const float* x      = (const float*)d_in[0];
  const float* cpe0_w = (const float*)d_in[1];
  const float* cpe0_b = (const float*)d_in[2];
  const float* cpe1_w = (const float*)d_in[3];
  const float* cpe1_b = (const float*)d_in[4];
  const float* ln1_g  = (const float*)d_in[5];
  const float* ln1_b  = (const float*)d_in[6];
  const float* ln2_g  = (const float*)d_in[7];
  const float* ln2_b  = (const float*)d_in[8];
  const float* qkv_w  = (const float*)d_in[9];
  const float* qkv_b  = (const float*)d_in[10];
  const float* proj_w = (const float*)d_in[11];
  const float* proj_b = (const float*)d_in[12];
  const float* fc1_w  = (const float*)d_in[13];
  const float* fc1_b  = (const float*)d_in[14];
  const float* fc2_w  = (const float*)d_in[15];
  const float* fc2_b  = (const float*)d_in[16];
  float* out = (float*)d_out;
  char* ws = (char*)d_ws;

  unsigned short* qkvwT  = (unsigned short*)(ws + 0);           // 1536x512 bf16
  unsigned short* projwT = (unsigned short*)(ws + 1572864);     // 512x512
  unsigned short* fc1wT  = (unsigned short*)(ws + 2097152);     // 2048x512
  unsigned short* fc2wT  = (unsigned short*)(ws + 4194304);     // 512x2048
  float*          shortc = (float*)(ws + 6291456);              // 50176x512 f32
  unsigned short* lnb    = (unsigned short*)(ws + 109051904);   // 50176x512 bf16
  unsigned short* qkvb   = (unsigned short*)(ws + 160432128);   // 50176x1536 bf16
  unsigned short* attnb  = (unsigned short*)(ws + 314572800);   // 50176x512 bf16
  unsigned short* gelub  = qkvb;   // overlay: 50176x2048 bf16
  float* h2 = out;                 // reuse d_out as h2 scratch

  wtranspose_kernel<<<(512 * 1536 + 255) / 256, 256, 0, stream>>>(qkv_w, qkvwT, 512, 1536);
  wtranspose_kernel<<<(512 * 512 + 255) / 256, 256, 0, stream>>>(proj_w, projwT, 512, 512);
  wtranspose_kernel<<<(512 * 2048 + 255) / 256, 256, 0, stream>>>(fc1_w, fc1wT, 512, 2048);
  wtranspose_kernel<<<(2048 * 512 + 255) / 256, 256, 0, stream>>>(fc2_w, fc2wT, 2048, 512);

  const int pixblocks = (BB * HH * WW * 128) / 256;   // 25088
  cpe_kernel<<<pixblocks, 256, 0, stream>>>(x, cpe0_w, cpe0_b, shortc);
  ln_kernel<<<NTOK / 4, 256, 0, stream>>>(shortc, ln1_g, ln1_b, lnb);
  gemm_kernel<0><<<dim3(12, 196), 512, 0, stream>>>(lnb, qkvwT, qkv_b, nullptr,
                                                    nullptr, qkvb, NTOK, 1536, 512);
  attn_mfma_kernel<<<8192, 64, 0, stream>>>(qkvb, attnb);
  gemm_kernel<1><<<dim3(4, 196), 512, 0, stream>>>(attnb, projwT, proj_b, shortc,
                                                   shortc, nullptr, NTOK, 512, 512);
  cpe_kernel<<<pixblocks, 256, 0, stream>>>(shortc, cpe1_w, cpe1_b, h2);
  ln_kernel<<<NTOK / 4, 256, 0, stream>>>(h2, ln2_g, ln2_b, lnb);
  gemm_kernel<2><<<dim3(16, 196), 512, 0, stream>>>(lnb, fc1wT, fc1_b, nullptr,
                                                    nullptr, gelub, NTOK, 2048, 512);
  gemm_kernel<1><<<dim3(4, 196), 512, 0, stream>>>(gelub, fc2wT, fc2_b, h2,
                                                   out, nullptr, NTOK, 512, 2048);
}

// Round 5
// 808.281 us; speedup vs baseline: 1.4336x; 1.0065x over previous
//
#include <hip/hip_runtime.h>
#include <stdint.h>

#define HH 112
#define WW 112
#define CC 512
#define BB 4
#define LLEN (HH*WW)
#define NTOK (BB*LLEN)   // 50176
#define NHEADS 8
#define HD 64
#define HIDDEN 2048

typedef __bf16 bf16x8 __attribute__((ext_vector_type(8)));
typedef float f32x4 __attribute__((ext_vector_type(4)));

__device__ __forceinline__ unsigned short f2bf(float x) {
  uint32_t u = __float_as_uint(x);
  u += 0x7fffu + ((u >> 16) & 1u);
  return (unsigned short)(u >> 16);
}
__device__ __forceinline__ float bf2f(unsigned short h) {
  return __uint_as_float((uint32_t)h << 16);
}

// async global->LDS, 16B per lane; lds dest must be wave-uniform base
__device__ __forceinline__ void gload16(const void* gptr, void* lptr) {
  __builtin_amdgcn_global_load_lds(
      (const __attribute__((address_space(1))) void*)gptr,
      (__attribute__((address_space(3))) void*)lptr,
      16, 0, 0);
}

// ---------------- weight transpose (K,N) f32 -> (N,K) bf16 ----------------
__global__ __launch_bounds__(256) void wtranspose_kernel(
    const float* __restrict__ w, unsigned short* __restrict__ wt, int K, int N) {
  int idx = blockIdx.x * 256 + threadIdx.x;
  if (idx >= K * N) return;
  int k = idx / N, n = idx - k * N;
  wt[(size_t)n * K + k] = f2bf(w[idx]);
}

// ---------------- depthwise 3x3 conv + bias + residual ----------------
__global__ __launch_bounds__(256) void cpe_kernel(
    const float* __restrict__ x, const float* __restrict__ w,
    const float* __restrict__ bias, float* __restrict__ out) {
  int tid = blockIdx.x * 256 + threadIdx.x;
  int c = (tid & 127) << 2;      // channel chunk of 4
  int pix = tid >> 7;
  int xx = pix % WW; int t2 = pix / WW; int yy = t2 % HH; int bb = t2 / HH;
  float4 bv = *(const float4*)(&bias[c]);
  float ax = bv.x, ay = bv.y, az = bv.z, aw = bv.w;
  #pragma unroll
  for (int ky = 0; ky < 3; ky++) {
    int y = yy + ky - 1;
    if ((unsigned)y >= (unsigned)HH) continue;
    #pragma unroll
    for (int kx = 0; kx < 3; kx++) {
      int x2 = xx + kx - 1;
      if ((unsigned)x2 >= (unsigned)WW) continue;
      const float4 v = *(const float4*)(&x[(((size_t)bb * HH + y) * WW + x2) * CC + c]);
      const float4 wv = *(const float4*)(&w[(ky * 3 + kx) * CC + c]);
      ax = fmaf(v.x, wv.x, ax); ay = fmaf(v.y, wv.y, ay);
      az = fmaf(v.z, wv.z, az); aw = fmaf(v.w, wv.w, aw);
    }
  }
  size_t o = (size_t)pix * CC + c;
  const float4 xv = *(const float4*)(&x[o]);
  float4 r; r.x = xv.x + ax; r.y = xv.y + ay; r.z = xv.z + az; r.w = xv.w + aw;
  *(float4*)(&out[o]) = r;
}

// ---------------- LayerNorm (C=512), one wave per token, bf16 out ----------------
__global__ __launch_bounds__(256) void ln_kernel(
    const float* __restrict__ in, const float* __restrict__ g,
    const float* __restrict__ b, unsigned short* __restrict__ out) {
  int token = (blockIdx.x * 256 + threadIdx.x) >> 6;
  int lane = threadIdx.x & 63;
  const float* row = in + (size_t)token * CC;
  float4 v0 = *(const float4*)(row + lane * 8);
  float4 v1 = *(const float4*)(row + lane * 8 + 4);
  float s = v0.x + v0.y + v0.z + v0.w + v1.x + v1.y + v1.z + v1.w;
  float ss = v0.x*v0.x + v0.y*v0.y + v0.z*v0.z + v0.w*v0.w
           + v1.x*v1.x + v1.y*v1.y + v1.z*v1.z + v1.w*v1.w;
  #pragma unroll
  for (int o = 32; o; o >>= 1) { s += __shfl_xor(s, o, 64); ss += __shfl_xor(ss, o, 64); }
  float mu = s * (1.f / CC);
  float var = ss * (1.f / CC) - mu * mu;
  float rs = rsqrtf(var + 1e-5f);
  float4 g0 = *(const float4*)(&g[lane * 8]);
  float4 g1 = *(const float4*)(&g[lane * 8 + 4]);
  float4 b0 = *(const float4*)(&b[lane * 8]);
  float4 b1 = *(const float4*)(&b[lane * 8 + 4]);
  unsigned short o8[8];
  o8[0] = f2bf((v0.x - mu) * rs * g0.x + b0.x);
  o8[1] = f2bf((v0.y - mu) * rs * g0.y + b0.y);
  o8[2] = f2bf((v0.z - mu) * rs * g0.z + b0.z);
  o8[3] = f2bf((v0.w - mu) * rs * g0.w + b0.w);
  o8[4] = f2bf((v1.x - mu) * rs * g1.x + b1.x);
  o8[5] = f2bf((v1.y - mu) * rs * g1.y + b1.y);
  o8[6] = f2bf((v1.z - mu) * rs * g1.z + b1.z);
  o8[7] = f2bf((v1.w - mu) * rs * g1.w + b1.w);
  uint4 pk;
  pk.x = (uint32_t)o8[0] | ((uint32_t)o8[1] << 16);
  pk.y = (uint32_t)o8[2] | ((uint32_t)o8[3] << 16);
  pk.z = (uint32_t)o8[4] | ((uint32_t)o8[5] << 16);
  pk.w = (uint32_t)o8[6] | ((uint32_t)o8[7] << 16);
  *(uint4*)(&out[(size_t)token * CC + lane * 8]) = pk;
}

// ---- bf16 MFMA GEMM: 3-buf, 2-ahead prefetch, counted vmcnt, T2 chunk-swizzle ----
// Tile 256x128, BK=32, 512 threads = 8 waves (4 row x 2 col), per-wave out 64x64.
// LDS chunk swizzle (rule-21: both sides): LDS[row][chunk] holds global
// [row][chunk ^ ((row>>1)&3)]; reads XOR the same. Per 16-lane phase all 8
// four-bank groups hit -> 2-way only (free).
// MODE 0: out bf16 = C + bias; MODE 1: out f32 = C+bias+res; MODE 2: bf16 gelu
#define BM 256
#define BN 128
#define BK 32

template <int MODE>
__global__ __launch_bounds__(512) void gemm_kernel(
    const unsigned short* __restrict__ A, const unsigned short* __restrict__ BT,
    const float* __restrict__ bias, const float* __restrict__ res,
    float* __restrict__ outF, unsigned short* __restrict__ outB,
    int M, int N, int K) {
  __shared__ unsigned short As[3][BM * BK];   // 3 x 16KB
  __shared__ unsigned short Bs[3][BN * BK];   // 3 x 8KB
  // XCD-aware swizzle (all grids divisible by 8)
  int nwg = gridDim.x * gridDim.y;
  int flat = blockIdx.y * gridDim.x + blockIdx.x;
  int swz = (flat & 7) * (nwg >> 3) + (flat >> 3);
  int bx = swz % gridDim.x, by = swz / gridDim.x;
  const int bm = by * BM, bn = bx * BN;
  const int t = threadIdx.x;
  const int wid = t >> 6, lane = t & 63;
  const int wr = wid >> 1, wc = wid & 1;        // 4x2 wave grid
  const int lr = lane & 15;
  // T2 read-side swizzle: chunk = (lane>>4) ^ ((lr>>1)&3); lk in elems
  const int lk = (((lane >> 4) ^ ((lane >> 1) & 3)) & 3) * 8;
  // staging: thread t covers row t>>2, global 16B chunk (t&3)^((row>>1)&3)
  const int srow = t >> 2;
  const int scol = (((t & 3) ^ ((t >> 3) & 3)) & 3) * 8;
  const size_t arow0 = (size_t)(bm + srow) * K + scol;          // A rows 0-127
  const size_t arow1 = (size_t)(bm + 128 + srow) * K + scol;    // A rows 128-255
  const size_t brow  = (size_t)(bn + srow) * K + scol;          // B rows 0-127
  const int ldsA0 = wid * 512;          // wave-uniform LDS dests (elems)
  const int ldsA1 = 4096 + wid * 512;
  const int ldsB  = wid * 512;

  f32x4 acc[4][4] = {};
  const int nt = K / BK;

  // prologue: stage tiles 0 and 1 (3 loads per thread each)
  gload16(&A[arow0],       &As[0][ldsA0]);
  gload16(&A[arow1],       &As[0][ldsA1]);
  gload16(&BT[brow],       &Bs[0][ldsB]);
  gload16(&A[arow0 + BK],  &As[1][ldsA0]);
  gload16(&A[arow1 + BK],  &As[1][ldsA1]);
  gload16(&BT[brow + BK],  &Bs[1][ldsB]);

  for (int tile = 0; tile < nt - 1; ++tile) {
    // wait for tile's 3 loads (allow tile+1's 3 to stay in flight), then sync.
    asm volatile("s_waitcnt vmcnt(3)" ::: "memory");
    __builtin_amdgcn_s_barrier();
    __builtin_amdgcn_sched_barrier(0);
    const unsigned short* as = As[tile % 3];
    const unsigned short* bs = Bs[tile % 3];
    bf16x8 af[4], bfr[4];
    #pragma unroll
    for (int i = 0; i < 4; i++)
      af[i] = *(const bf16x8*)(&as[(wr * 64 + i * 16 + lr) * BK + lk]);
    #pragma unroll
    for (int j = 0; j < 4; j++)
      bfr[j] = *(const bf16x8*)(&bs[(wc * 64 + j * 16 + lr) * BK + lk]);
    // issue prefetch of tile+2 (overwrites buf[(tile-1)%3]; safe after barrier)
    if (tile + 2 < nt) {
      int kt = (tile + 2) * BK;
      int nb = (tile + 2) % 3;
      gload16(&A[arow0 + kt], &As[nb][ldsA0]);
      gload16(&A[arow1 + kt], &As[nb][ldsA1]);
      gload16(&BT[brow + kt], &Bs[nb][ldsB]);
    }
    __builtin_amdgcn_s_setprio(1);
    #pragma unroll
    for (int i = 0; i < 4; i++)
      #pragma unroll
      for (int j = 0; j < 4; j++)
        acc[i][j] = __builtin_amdgcn_mfma_f32_16x16x32_bf16(af[i], bfr[j], acc[i][j], 0, 0, 0);
    __builtin_amdgcn_s_setprio(0);
  }
  // final tile: drain everything
  {
    asm volatile("s_waitcnt vmcnt(0)" ::: "memory");
    __builtin_amdgcn_s_barrier();
    __builtin_amdgcn_sched_barrier(0);
    const unsigned short* as = As[(nt - 1) % 3];
    const unsigned short* bs = Bs[(nt - 1) % 3];
    bf16x8 af[4], bfr[4];
    #pragma unroll
    for (int i = 0; i < 4; i++)
      af[i] = *(const bf16x8*)(&as[(wr * 64 + i * 16 + lr) * BK + lk]);
    #pragma unroll
    for (int j = 0; j < 4; j++)
      bfr[j] = *(const bf16x8*)(&bs[(wc * 64 + j * 16 + lr) * BK + lk]);
    #pragma unroll
    for (int i = 0; i < 4; i++)
      #pragma unroll
      for (int j = 0; j < 4; j++)
        acc[i][j] = __builtin_amdgcn_mfma_f32_16x16x32_bf16(af[i], bfr[j], acc[i][j], 0, 0, 0);
  }

  const int orow = (lane >> 4) * 4, ocol = lane & 15;
  #pragma unroll
  for (int i = 0; i < 4; i++) {
    #pragma unroll
    for (int j = 0; j < 4; j++) {
      int gc = bn + wc * 64 + j * 16 + ocol;
      float bv = bias[gc];
      #pragma unroll
      for (int r = 0; r < 4; r++) {
        int gr = bm + wr * 64 + i * 16 + orow + r;
        size_t off = (size_t)gr * N + gc;
        float v = acc[i][j][r] + bv;
        if (MODE == 0) {
          outB[off] = f2bf(v);
        } else if (MODE == 1) {
          outF[off] = v + res[off];
        } else {
          float u = 0.79788456080286536f * (v + 0.044715f * v * v * v);
          float e = __expf(2.f * u);
          float th = 1.f - 2.f / (e + 1.f);
          outB[off] = f2bf(0.5f * v * (1.f + th));
        }
      }
    }
  }
}

// ---------------- MFMA window attention: 1 wave per (window, head) ----------------
#define WNS 68   // LDS row stride (elems): 136B = 8B aligned, odd-dword for banks

__global__ __launch_bounds__(64) void attn_mfma_kernel(
    const unsigned short* __restrict__ qkv, unsigned short* __restrict__ out) {
  __shared__ unsigned short VT[64 * WNS];   // V^T: [d][k]
  __shared__ unsigned short Ps[64 * WNS];   // P:   [q][k]
  const int task = blockIdx.x;
  const int win = task >> 3, h = task & 7;
  const int b = win >> 8, wy = (win >> 4) & 15, wx = win & 15;
  const int lane = threadIdx.x;
  const int lr = lane & 15, g = lane >> 4;

  auto tokof = [&](int r) {
    int rr = r > 48 ? 48 : r;
    int y = rr / 7, x2 = rr - y * 7;
    return (size_t)(b * LLEN + (wy * 7 + y) * WW + wx * 7 + x2);
  };

  // ---- stage V^T (scalar writes: per-instruction row base uniform -> conflict-free)
  {
    size_t vbase = tokof(lane) * 1536 + h * 64 + 1024;
    bool valid = lane <= 48;
    #pragma unroll
    for (int c = 0; c < 8; c++) {
      uint4 v = *(const uint4*)(&qkv[vbase + c * 8]);
      const unsigned short* pv = (const unsigned short*)&v;
      #pragma unroll
      for (int e = 0; e < 8; e++)
        VT[(c * 8 + e) * WNS + lane] = valid ? pv[e] : (unsigned short)0;
    }
  }

  // ---- Q,K fragments straight from global (A/B frag rows = lr + 16*tile)
  size_t tok[4];
  #pragma unroll
  for (int i2 = 0; i2 < 4; i2++) tok[i2] = tokof(i2 * 16 + lr);
  bf16x8 Qf[4][2], Kf[4][2];
  #pragma unroll
  for (int i2 = 0; i2 < 4; i2++) {
    size_t base = tok[i2] * 1536 + h * 64 + g * 8;
    #pragma unroll
    for (int ks = 0; ks < 2; ks++) {
      Qf[i2][ks] = *(const bf16x8*)(&qkv[base + ks * 32]);
      Kf[i2][ks] = *(const bf16x8*)(&qkv[base + 512 + ks * 32]);
    }
  }

  // ---- S^T = K·Q^T : acc[i=k-tile][j=q-tile], C row = k, col = q
  f32x4 acc[4][4] = {};
  #pragma unroll
  for (int ks = 0; ks < 2; ks++)
    #pragma unroll
    for (int i2 = 0; i2 < 4; i2++)
      #pragma unroll
      for (int j = 0; j < 4; j++)
        acc[i2][j] = __builtin_amdgcn_mfma_f32_16x16x32_bf16(Kf[i2][ks], Qf[j][ks], acc[i2][j], 0, 0, 0);

  // ---- softmax over k (row axis of S^T): in-reg over 16 vals + shfl 16,32
  #pragma unroll
  for (int j = 0; j < 4; j++) {
    float mx = -1e30f;
    #pragma unroll
    for (int i2 = 0; i2 < 4; i2++)
      #pragma unroll
      for (int r = 0; r < 4; r++) {
        int k = 16 * i2 + 4 * g + r;
        mx = fmaxf(mx, (k <= 48) ? acc[i2][j][r] : -1e30f);
      }
    mx = fmaxf(mx, __shfl_xor(mx, 16, 64));
    mx = fmaxf(mx, __shfl_xor(mx, 32, 64));
    float p[4][4];
    float sum = 0.f;
    #pragma unroll
    for (int i2 = 0; i2 < 4; i2++)
      #pragma unroll
      for (int r = 0; r < 4; r++) {
        int k = 16 * i2 + 4 * g + r;
        float e = (k <= 48) ? __expf(0.125f * (acc[i2][j][r] - mx)) : 0.f;
        p[i2][r] = e; sum += e;
      }
    sum += __shfl_xor(sum, 16, 64);
    sum += __shfl_xor(sum, 32, 64);
    float inv = 1.f / sum;
    int q = 16 * j + lr;
    #pragma unroll
    for (int i2 = 0; i2 < 4; i2++) {
      uint2 w;
      w.x = (uint32_t)f2bf(p[i2][0] * inv) | ((uint32_t)f2bf(p[i2][1] * inv) << 16);
      w.y = (uint32_t)f2bf(p[i2][2] * inv) | ((uint32_t)f2bf(p[i2][3] * inv) << 16);
      *(uint2*)(&Ps[q * WNS + 16 * i2 + 4 * g]) = w;
    }
  }

  __syncthreads();   // VT + Ps writes -> reads fence

  // ---- O = P·V : A = P[q][k], B^T = VT[d][k]; o[i=q-tile][j=d-tile]
  f32x4 o[4][4] = {};
  #pragma unroll
  for (int ks = 0; ks < 2; ks++) {
    bf16x8 Pf[4], Vf[4];
    #pragma unroll
    for (int i2 = 0; i2 < 4; i2++) {
      int base = (16 * i2 + lr) * WNS + ks * 32 + g * 8;
      uint2 lo = *(const uint2*)(&Ps[base]);
      uint2 hi = *(const uint2*)(&Ps[base + 4]);
      uint4 u; u.x = lo.x; u.y = lo.y; u.z = hi.x; u.w = hi.y;
      Pf[i2] = *(bf16x8*)&u;
    }
    #pragma unroll
    for (int j = 0; j < 4; j++) {
      int base = (16 * j + lr) * WNS + ks * 32 + g * 8;
      uint2 lo = *(const uint2*)(&VT[base]);
      uint2 hi = *(const uint2*)(&VT[base + 4]);
      uint4 u; u.x = lo.x; u.y = lo.y; u.z = hi.x; u.w = hi.y;
      Vf[j] = *(bf16x8*)&u;
    }
    #pragma unroll
    for (int i2 = 0; i2 < 4; i2++)
      #pragma unroll
      for (int j = 0; j < 4; j++)
        o[i2][j] = __builtin_amdgcn_mfma_f32_16x16x32_bf16(Pf[i2], Vf[j], o[i2][j], 0, 0, 0);
  }

  // ---- store O rows q<49
  #pragma unroll
  for (int i2 = 0; i2 < 4; i2++)
    #pragma unroll
    for (int r = 0; r < 4; r++) {
      int q = 16 * i2 + 4 * g + r;
      if (q <= 48) {
        size_t obase = tokof(q) * 512 + h * 64 + lr;
        #pragma unroll
        for (int j = 0; j < 4; j++)
          out[obase + 16 * j] = f2bf(o[i2][j][r]);
      }
    }
}

extern "C" void kernel_launch(void* const* d_in, const int* in_sizes, int n_in,
                              void* d_out, int out_size, void* d_ws, size_t ws_size,
                              hipStream_t stream) {
  const float* x      = (const float*)d_in[0];
  const float* cpe0_w = (const float*)d_in[1];
  const float* cpe0_b = (const float*)d_in[2];
  const float* cpe1_w = (const float*)d_in[3];
  const float* cpe1_b = (const float*)d_in[4];
  const float* ln1_g  = (const float*)d_in[5];
  const float* ln1_b  = (const float*)d_in[6];
  const float* ln2_g  = (const float*)d_in[7];
  const float* ln2_b  = (const float*)d_in[8];
  const float* qkv_w  = (const float*)d_in[9];
  const float* qkv_b  = (const float*)d_in[10];
  const float* proj_w = (const float*)d_in[11];
  const float* proj_b = (const float*)d_in[12];
  const float* fc1_w  = (const float*)d_in[13];
  const float* fc1_b  = (const float*)d_in[14];
  const float* fc2_w  = (const float*)d_in[15];
  const float* fc2_b  = (const float*)d_in[16];
  float* out = (float*)d_out;
  char* ws = (char*)d_ws;

  unsigned short* qkvwT  = (unsigned short*)(ws + 0);           // 1536x512 bf16
  unsigned short* projwT = (unsigned short*)(ws + 1572864);     // 512x512
  unsigned short* fc1wT  = (unsigned short*)(ws + 2097152);     // 2048x512
  unsigned short* fc2wT  = (unsigned short*)(ws + 4194304);     // 512x2048
  float*          shortc = (float*)(ws + 6291456);              // 50176x512 f32
  unsigned short* lnb    = (unsigned short*)(ws + 109051904);   // 50176x512 bf16
  unsigned short* qkvb   = (unsigned short*)(ws + 160432128);   // 50176x1536 bf16
  unsigned short* attnb  = (unsigned short*)(ws + 314572800);   // 50176x512 bf16
  unsigned short* gelub  = qkvb;   // overlay: 50176x2048 bf16
  float* h2 = out;                 // reuse d_out as h2 scratch

  wtranspose_kernel<<<(512 * 1536 + 255) / 256, 256, 0, stream>>>(qkv_w, qkvwT, 512, 1536);
  wtranspose_kernel<<<(512 * 512 + 255) / 256, 256, 0, stream>>>(proj_w, projwT, 512, 512);
  wtranspose_kernel<<<(512 * 2048 + 255) / 256, 256, 0, stream>>>(fc1_w, fc1wT, 512, 2048);
  wtranspose_kernel<<<(2048 * 512 + 255) / 256, 256, 0, stream>>>(fc2_w, fc2wT, 2048, 512);

  const int pixblocks = (BB * HH * WW * 128) / 256;   // 25088
  cpe_kernel<<<pixblocks, 256, 0, stream>>>(x, cpe0_w, cpe0_b, shortc);
  ln_kernel<<<NTOK / 4, 256, 0, stream>>>(shortc, ln1_g, ln1_b, lnb);
  gemm_kernel<0><<<dim3(12, 196), 512, 0, stream>>>(lnb, qkvwT, qkv_b, nullptr,
                                                    nullptr, qkvb, NTOK, 1536, 512);
  attn_mfma_kernel<<<8192, 64, 0, stream>>>(qkvb, attnb);
  gemm_kernel<1><<<dim3(4, 196), 512, 0, stream>>>(attnb, projwT, proj_b, shortc,
                                                   shortc, nullptr, NTOK, 512, 512);
  cpe_kernel<<<pixblocks, 256, 0, stream>>>(shortc, cpe1_w, cpe1_b, h2);
  ln_kernel<<<NTOK / 4, 256, 0, stream>>>(h2, ln2_g, ln2_b, lnb);
  gemm_kernel<2><<<dim3(16, 196), 512, 0, stream>>>(lnb, fc1wT, fc1_b, nullptr,
                                                    nullptr, gelub, NTOK, 2048, 512);
  gemm_kernel<1><<<dim3(4, 196), 512, 0, stream>>>(gelub, fc2wT, fc2_b, h2,
                                                   out, nullptr, NTOK, 512, 2048);
}